// Round 1
// baseline (4062.752 us; speedup 1.0000x reference)
//
#include <hip/hip_runtime.h>
#include <math.h>

#define BN_EPS 1e-5f

// ---------------------------------------------------------------------------
// Edge pass 1: in-degree count + scatter-sum of pos[src] into sum1[dst]
// ---------------------------------------------------------------------------
__global__ void k_deg_sum1(const int* __restrict__ src, const int* __restrict__ dst,
                           const float* __restrict__ pos, float* __restrict__ cnt,
                           float* __restrict__ sum1, int E) {
  int e = blockIdx.x * blockDim.x + threadIdx.x;
  if (e >= E) return;
  int s = src[e], d = dst[e];
  atomicAdd(&cnt[d], 1.f);
  atomicAdd(&sum1[d * 3 + 0], pos[s * 3 + 0]);
  atomicAdd(&sum1[d * 3 + 1], pos[s * 3 + 1]);
  atomicAdd(&sum1[d * 3 + 2], pos[s * 3 + 2]);
}

// ---------------------------------------------------------------------------
// SAGE1: x1 = relu(wl @ (sum1/cnt) + wr @ pos + b), written to xcat[:,0:128]
// one block (128 threads) per node
// ---------------------------------------------------------------------------
__global__ void k_sage1(const float* __restrict__ sum1, const float* __restrict__ cnt,
                        const float* __restrict__ pos,
                        const float* __restrict__ wl, const float* __restrict__ wr,
                        const float* __restrict__ b, float* __restrict__ xcat, int N) {
  int n = blockIdx.x;
  if (n >= N) return;
  int o = threadIdx.x;  // 0..127
  float c = fmaxf(cnt[n], 1.f);
  float a0 = sum1[n * 3 + 0] / c, a1 = sum1[n * 3 + 1] / c, a2 = sum1[n * 3 + 2] / c;
  float p0 = pos[n * 3 + 0], p1 = pos[n * 3 + 1], p2 = pos[n * 3 + 2];
  float v = b[o] + wl[o * 3 + 0] * a0 + wl[o * 3 + 1] * a1 + wl[o * 3 + 2] * a2
                 + wr[o * 3 + 0] * p0 + wr[o * 3 + 1] * p1 + wr[o * 3 + 2] * p2;
  xcat[(size_t)n * 256 + o] = fmaxf(v, 0.f);
}

// ---------------------------------------------------------------------------
// Edge pass 2: sum2[dst] += x1[src]  (wave per edge, float2 per lane)
// ---------------------------------------------------------------------------
__global__ void k_edge2(const int* __restrict__ src, const int* __restrict__ dst,
                        const float* __restrict__ xcat, float* __restrict__ sum2, int E) {
  int gw = (blockIdx.x * blockDim.x + threadIdx.x) >> 6;
  int nw = (gridDim.x * blockDim.x) >> 6;
  int lane = threadIdx.x & 63;
  for (int e = gw; e < E; e += nw) {
    int s = src[e], d = dst[e];
    float2 v = *(const float2*)&xcat[(size_t)s * 256 + lane * 2];
    atomicAdd(&sum2[(size_t)d * 128 + lane * 2 + 0], v.x);
    atomicAdd(&sum2[(size_t)d * 128 + lane * 2 + 1], v.y);
  }
}

// sum2 /= max(cnt,1)  (elementwise)
__global__ void k_norm_sum2(float* __restrict__ sum2, const float* __restrict__ cnt, int N) {
  size_t i = (size_t)blockIdx.x * blockDim.x + threadIdx.x;
  if (i >= (size_t)N * 128) return;
  int n = (int)(i >> 7);
  sum2[i] /= fmaxf(cnt[n], 1.f);
}

// ---------------------------------------------------------------------------
// Generic tiled fp32 GEMM: C[n, co+m] = act( sum_k Acat(n,k)*W(m,k) + bias[m] )
// Acat = [A1 (K1 cols, stride as1) | A2 (K2 cols, stride as2)]
// W given as two row-major blocks W1[M,K1], W2[M,K2].
// BM=128 rows x BN=64 cols per block, 256 threads, 8x4 micro-tile, BK=16.
// ---------------------------------------------------------------------------
#define GBM 128
#define GBN 64
#define GBK 16
__global__ __launch_bounds__(256) void gemm_cat(
    const float* __restrict__ A1, int as1, int K1,
    const float* __restrict__ A2, int as2, int K2,
    const float* __restrict__ W1, const float* __restrict__ W2,
    const float* __restrict__ bias, float* __restrict__ C, int cs, int co,
    int Nr, int M, int relu) {
  __shared__ float As[GBK][GBM + 4];
  __shared__ float Bs[GBK][GBN + 4];
  int tid = threadIdx.x;
  int bm = blockIdx.x, bn = blockIdx.y;
  int tx = tid & 15, ty = tid >> 4;
  int K = K1 + K2;

  float acc[8][4];
#pragma unroll
  for (int i = 0; i < 8; i++)
#pragma unroll
    for (int j = 0; j < 4; j++) acc[i][j] = 0.f;

  int kk = tid & 15;
  int rowg = tid >> 4;

  for (int kt = 0; kt < K; kt += GBK) {
    int kg = kt + kk;
    // select source for this k column
    const float* Ap;
    int ast, kl;
    if (kg < K1) { Ap = A1; ast = as1; kl = kg; }
    else         { Ap = A2; ast = as2; kl = kg - K1; }
    const float* Wp;
    int wst, wk;
    if (kg < K1) { Wp = W1; wst = K1; wk = kg; }
    else         { Wp = W2; wst = K2; wk = kg - K1; }
#pragma unroll
    for (int t = 0; t < 8; t++) {
      int i = rowg + t * 16;
      int n = bm * GBM + i;
      As[kk][i] = (n < Nr) ? Ap[(size_t)n * ast + kl] : 0.f;
    }
#pragma unroll
    for (int t = 0; t < 4; t++) {
      int m = rowg + t * 16;
      int gm = bn * GBN + m;
      Bs[kk][m] = (gm < M) ? Wp[(size_t)gm * wst + wk] : 0.f;
    }
    __syncthreads();
#pragma unroll
    for (int k = 0; k < GBK; k++) {
      float4 a0 = *(const float4*)&As[k][ty * 8];
      float4 a1 = *(const float4*)&As[k][ty * 8 + 4];
      float4 b0 = *(const float4*)&Bs[k][tx * 4];
      float av[8] = {a0.x, a0.y, a0.z, a0.w, a1.x, a1.y, a1.z, a1.w};
      float bv[4] = {b0.x, b0.y, b0.z, b0.w};
#pragma unroll
      for (int i = 0; i < 8; i++)
#pragma unroll
        for (int j = 0; j < 4; j++) acc[i][j] += av[i] * bv[j];
    }
    __syncthreads();
  }

#pragma unroll
  for (int i = 0; i < 8; i++) {
    int n = bm * GBM + ty * 8 + i;
    if (n >= Nr) continue;
#pragma unroll
    for (int j = 0; j < 4; j++) {
      int gm = bn * GBN + tx * 4 + j;
      if (gm >= M) continue;
      float v = acc[i][j];
      if (bias) v += bias[gm];
      if (relu) v = fmaxf(v, 0.f);
      C[(size_t)n * cs + co + gm] = v;
    }
  }
}

// ---------------------------------------------------------------------------
// GAT attention coefficients: a_src[n,h], a_dst[n,h] (wave per node)
// attn layout: [n][0]=as0 [1]=as1 [2]=ad0 [3]=ad1
// ---------------------------------------------------------------------------
__global__ void k_attn(const float* __restrict__ xw, const float* __restrict__ asrc,
                       const float* __restrict__ adst, float* __restrict__ attn, int N) {
  int w = (blockIdx.x * blockDim.x + threadIdx.x) >> 6;
  int nw = (gridDim.x * blockDim.x) >> 6;
  int lane = threadIdx.x & 63;
  for (int n = w; n < N; n += nw) {
    float4 x = *(const float4*)&xw[(size_t)n * 256 + lane * 4];
    float4 a = *(const float4*)&asrc[lane * 4];
    float4 d = *(const float4*)&adst[lane * 4];
    float ps = x.x * a.x + x.y * a.y + x.z * a.z + x.w * a.w;
    float pd = x.x * d.x + x.y * d.y + x.z * d.z + x.w * d.w;
#pragma unroll
    for (int m = 16; m >= 1; m >>= 1) {
      ps += __shfl_xor(ps, m);
      pd += __shfl_xor(pd, m);
    }
    if (lane == 0)       { attn[n * 4 + 0] = ps; attn[n * 4 + 2] = pd; }
    else if (lane == 32) { attn[n * 4 + 1] = ps; attn[n * 4 + 3] = pd; }
  }
}

// ---------------------------------------------------------------------------
// GAT edge pass: numer[d] += exp(leaky(e)) * xw[s]; denom[d,h] += w
// (softmax shift-invariance: skipping segment-max is mathematically identical)
// wave per edge, float4 per lane (256 channels = 2 heads x 128)
// ---------------------------------------------------------------------------
__global__ void k_gat_edge(const int* __restrict__ src, const int* __restrict__ dst,
                           const float* __restrict__ xw, const float* __restrict__ attn,
                           float* __restrict__ numer, float* __restrict__ denom, int E) {
  int gw = (blockIdx.x * blockDim.x + threadIdx.x) >> 6;
  int nw = (gridDim.x * blockDim.x) >> 6;
  int lane = threadIdx.x & 63;
  int h = lane >> 5;
  for (int e = gw; e < E; e += nw) {
    int s = src[e], d = dst[e];
    float ea = attn[s * 4 + h] + attn[d * 4 + 2 + h];
    float el = ea >= 0.f ? ea : 0.2f * ea;
    float wgt = expf(el);
    float4 xv = *(const float4*)&xw[(size_t)s * 256 + lane * 4];
    size_t base = (size_t)d * 256 + lane * 4;
    atomicAdd(&numer[base + 0], wgt * xv.x);
    atomicAdd(&numer[base + 1], wgt * xv.y);
    atomicAdd(&numer[base + 2], wgt * xv.z);
    atomicAdd(&numer[base + 3], wgt * xv.w);
    if (lane == 0 || lane == 32) atomicAdd(&denom[d * 2 + h], wgt);
  }
}

// ---------------------------------------------------------------------------
// GAT finalize: fold in self-loop, divide, head-mean, + g_b  (block per node)
// ---------------------------------------------------------------------------
__global__ void k_gat_final(const float* __restrict__ numer, const float* __restrict__ denom,
                            const float* __restrict__ xw, const float* __restrict__ attn,
                            const float* __restrict__ cnt, const float* __restrict__ gb,
                            float* __restrict__ x3g, int N) {
  int n = blockIdx.x;
  if (n >= N) return;
  int c = threadIdx.x;  // 0..127
  float as0 = attn[n * 4 + 0], as1 = attn[n * 4 + 1];
  float ad0 = attn[n * 4 + 2], ad1 = attn[n * 4 + 3];
  float e0 = as0 + ad0; e0 = e0 >= 0.f ? e0 : 0.2f * e0;
  float e1 = as1 + ad1; e1 = e1 >= 0.f ? e1 : 0.2f * e1;
  float w0 = expf(e0), w1 = expf(e1);
  float D0 = denom[n * 2 + 0] + w0;
  float D1 = denom[n * 2 + 1] + w1;
  float T0 = numer[(size_t)n * 256 + c] + w0 * xw[(size_t)n * 256 + c];
  float T1 = numer[(size_t)n * 256 + 128 + c] + w1 * xw[(size_t)n * 256 + 128 + c];
  float csl = cnt[n] + 1.f;
  x3g[(size_t)n * 128 + c] = 0.5f * (T0 / D0 + T1 / D1) / csl + gb[c];
}

// ---------------------------------------------------------------------------
// Global mean pool over sorted batch: run-length accumulate, flush on change
// 128 threads = one channel each; block owns a contiguous node chunk
// ---------------------------------------------------------------------------
__global__ void k_pool(const float* __restrict__ x3g, const int* __restrict__ batch,
                       float* __restrict__ zsum, float* __restrict__ zcnt, int N) {
  int t = threadIdx.x;  // 0..127
  int chunk = (N + gridDim.x - 1) / gridDim.x;
  int n0 = blockIdx.x * chunk;
  int n1 = min(N, n0 + chunk);
  if (n0 >= n1) return;
  int cur = batch[n0];
  float acc = 0.f, cacc = 0.f;
  for (int n = n0; n < n1; n++) {
    int b = batch[n];
    if (b != cur) {
      atomicAdd(&zsum[cur * 128 + t], acc);
      if (t == 0) atomicAdd(&zcnt[cur], cacc);
      acc = 0.f; cacc = 0.f; cur = b;
    }
    acc += x3g[(size_t)n * 128 + t];
    cacc += 1.f;
  }
  atomicAdd(&zsum[cur * 128 + t], acc);
  if (t == 0) atomicAdd(&zcnt[cur], cacc);
}

__global__ void k_zmean(const float* __restrict__ zsum, const float* __restrict__ zcnt,
                        float* __restrict__ zmean, int Bn) {
  int i = blockIdx.x * blockDim.x + threadIdx.x;
  if (i >= Bn * 128) return;
  int b = i >> 7;
  zmean[i] = zsum[i] / fmaxf(zcnt[b], 1.f);
}

// ---------------------------------------------------------------------------
// Decoder layer: Y = BN(X @ W.T + b) [relu], single block of 256 threads.
// Optionally writes result to `out` and argmax (as float) to `argout`.
// ---------------------------------------------------------------------------
__global__ void dec_layer(const float* __restrict__ X, float* __restrict__ Y,
                          const float* __restrict__ W, const float* __restrict__ bias,
                          const float* __restrict__ g, const float* __restrict__ beta,
                          int Ki, int Mo, int Bn, int relu,
                          float* __restrict__ out, float* __restrict__ argout) {
  int tid = threadIdx.x;
  for (int o = tid; o < Bn * Mo; o += blockDim.x) {
    int r = o / Mo, m = o - r * Mo;
    float acc = bias[m];
    const float* xr = &X[(size_t)r * Ki];
    const float* wr = &W[(size_t)m * Ki];
    for (int k = 0; k < Ki; k += 4) {
      float4 xv = *(const float4*)&xr[k];
      float4 wv = *(const float4*)&wr[k];
      acc += xv.x * wv.x + xv.y * wv.y + xv.z * wv.z + xv.w * wv.w;
    }
    Y[o] = acc;
  }
  __syncthreads();
  for (int m = tid; m < Mo; m += blockDim.x) {
    float mean = 0.f;
    for (int r = 0; r < Bn; r++) mean += Y[r * Mo + m];
    mean /= (float)Bn;
    float var = 0.f;
    for (int r = 0; r < Bn; r++) {
      float dv = Y[r * Mo + m] - mean;
      var += dv * dv;
    }
    var /= (float)Bn;
    float sc = g[m] / sqrtf(var + BN_EPS);
    float sh = beta[m] - mean * sc;
    for (int r = 0; r < Bn; r++) {
      float v = Y[r * Mo + m] * sc + sh;
      if (relu) v = fmaxf(v, 0.f);
      Y[r * Mo + m] = v;
      if (out) out[r * Mo + m] = v;
    }
  }
  if (argout) {
    __syncthreads();
    if (tid < Bn) {
      const float* yr = &Y[tid * Mo];
      float best = yr[0];
      int bi = 0;
      for (int j = 1; j < Mo; j++)
        if (yr[j] > best) { best = yr[j]; bi = j; }
      argout[tid] = (float)bi;
    }
  }
}

// ---------------------------------------------------------------------------
extern "C" void kernel_launch(void* const* d_in, const int* in_sizes, int n_in,
                              void* d_out, int out_size, void* d_ws, size_t ws_size,
                              hipStream_t stream) {
  const int N = in_sizes[0] / 3;
  const int E = in_sizes[1] / 2;
  const int Bn = out_size / 41;  // z [B,40] + argmax [B]

  const float* pos = (const float*)d_in[0];
  const int* ei = (const int*)d_in[1];
  const int* src = ei;
  const int* dst = ei + E;
  const int* batch = (const int*)d_in[2];
  const float* s1_wl = (const float*)d_in[3];
  const float* s1_wr = (const float*)d_in[4];
  const float* s1_b  = (const float*)d_in[5];
  const float* s2_wl = (const float*)d_in[6];
  const float* s2_wr = (const float*)d_in[7];
  const float* s2_b  = (const float*)d_in[8];
  const float* g_w    = (const float*)d_in[9];
  const float* g_asrc = (const float*)d_in[10];
  const float* g_adst = (const float*)d_in[11];
  const float* g_b    = (const float*)d_in[12];
  const float* d1_w = (const float*)d_in[13];
  const float* d1_b = (const float*)d_in[14];
  const float* bn1_g = (const float*)d_in[15];
  const float* bn1_b = (const float*)d_in[16];
  const float* d2_w = (const float*)d_in[17];
  const float* d2_b = (const float*)d_in[18];
  const float* bn2_g = (const float*)d_in[19];
  const float* bn2_b = (const float*)d_in[20];
  const float* d3_w = (const float*)d_in[21];
  const float* d3_b = (const float*)d_in[22];
  const float* bn3_g = (const float*)d_in[23];
  const float* bn3_b = (const float*)d_in[24];

  float* w = (float*)d_ws;
  size_t Ns = (size_t)N;
  float* cnt   = w;              // N
  float* sum1  = w + Ns;         // 3N
  float* xcat  = w + 4 * Ns;     // 256N  (x1|x2; later reused as GAT numer)
  float* sum2  = w + 260 * Ns;   // 128N  (mean agg; later reused as x3gat)
  float* xw    = w + 388 * Ns;   // 256N
  float* attn  = w + 644 * Ns;   // 4N
  float* denom = w + 648 * Ns;   // 2N
  float* base  = w + 650 * Ns;
  float* zsum  = base;            // Bn*128
  float* zcnt  = base + 8192;     // Bn
  float* zmean = base + 8256;     // Bn*128
  float* db1   = base + 16448;    // Bn*256
  float* db2   = db1 + 16384;     // Bn*128
  float* db3   = db2 + 8192;      // Bn*40
  float* out = (float*)d_out;

  // zero accumulators
  hipMemsetAsync(w, 0, 4 * Ns * sizeof(float), stream);          // cnt + sum1
  hipMemsetAsync(sum2, 0, 128 * Ns * sizeof(float), stream);
  hipMemsetAsync(denom, 0, 2 * Ns * sizeof(float), stream);
  hipMemsetAsync(zsum, 0, (8192 + 64) * sizeof(float), stream);

  k_deg_sum1<<<(E + 255) / 256, 256, 0, stream>>>(src, dst, pos, cnt, sum1, E);
  k_sage1<<<N, 128, 0, stream>>>(sum1, cnt, pos, s1_wl, s1_wr, s1_b, xcat, N);
  k_edge2<<<2048, 256, 0, stream>>>(src, dst, xcat, sum2, E);
  k_norm_sum2<<<(int)((128 * Ns + 255) / 256), 256, 0, stream>>>(sum2, cnt, N);

  // SAGE2: x2 = relu([m|x1] @ [wl|wr].T + b) -> xcat[:,128:256]
  dim3 g2((N + GBM - 1) / GBM, 128 / GBN);
  gemm_cat<<<g2, 256, 0, stream>>>(sum2, 128, 128, xcat, 256, 128,
                                   s2_wl, s2_wr, s2_b, xcat, 256, 128, N, 128, 1);

  // GAT projection: xw = xcat @ g_w.T
  dim3 g3((N + GBM - 1) / GBM, 256 / GBN);
  gemm_cat<<<g3, 256, 0, stream>>>(xcat, 256, 256, nullptr, 0, 0,
                                   g_w, nullptr, nullptr, xw, 256, 0, N, 256, 0);

  // xcat region becomes GAT numerator accumulator
  hipMemsetAsync(xcat, 0, 256 * Ns * sizeof(float), stream);

  k_attn<<<(N + 3) / 4, 256, 0, stream>>>(xw, g_asrc, g_adst, attn, N);
  k_gat_edge<<<4096, 256, 0, stream>>>(src, dst, xw, attn, xcat, denom, E);
  k_gat_final<<<N, 128, 0, stream>>>(xcat, denom, xw, attn, cnt, g_b, sum2, N);

  k_pool<<<128, 128, 0, stream>>>(sum2, batch, zsum, zcnt, N);
  k_zmean<<<(Bn * 128 + 255) / 256, 256, 0, stream>>>(zsum, zcnt, zmean, Bn);

  dec_layer<<<1, 256, 0, stream>>>(zmean, db1, d1_w, d1_b, bn1_g, bn1_b,
                                   128, 256, Bn, 1, nullptr, nullptr);
  dec_layer<<<1, 256, 0, stream>>>(db1, db2, d2_w, d2_b, bn2_g, bn2_b,
                                   256, 128, Bn, 1, nullptr, nullptr);
  dec_layer<<<1, 256, 0, stream>>>(db2, db3, d3_w, d3_b, bn3_g, bn3_b,
                                   128, 40, Bn, 0, out, out + Bn * 40);
}

// Round 2
// 2090.942 us; speedup vs baseline: 1.9430x; 1.9430x over previous
//
#include <hip/hip_runtime.h>
#include <math.h>

#define BN_EPS 1e-5f

// ---------------------------------------------------------------------------
// Edge pass 1: int in-degree + scatter-sum of pos[src] into sum1[dst]
// (pos scatter is only 1.5M float atomics on a 1.2MB array -> L2-resident)
// ---------------------------------------------------------------------------
__global__ void k_deg_sum1(const int* __restrict__ src, const int* __restrict__ dst,
                           const float* __restrict__ pos, int* __restrict__ deg,
                           float* __restrict__ sum1, int E) {
  int e = blockIdx.x * blockDim.x + threadIdx.x;
  if (e >= E) return;
  int s = src[e], d = dst[e];
  atomicAdd(&deg[d], 1);
  atomicAdd(&sum1[d * 3 + 0], pos[s * 3 + 0]);
  atomicAdd(&sum1[d * 3 + 1], pos[s * 3 + 1]);
  atomicAdd(&sum1[d * 3 + 2], pos[s * 3 + 2]);
}

// ---------------------------------------------------------------------------
// Exclusive scan of deg -> rowptr (3 tiny kernels, 1024 elems/block)
// ---------------------------------------------------------------------------
__global__ void k_scan1(const int* __restrict__ deg, int* __restrict__ rowptr,
                        int* __restrict__ bsum, int N) {
  __shared__ int part[256];
  int t = threadIdx.x;
  int base = blockIdx.x * 1024;
  int v[4]; int s = 0;
#pragma unroll
  for (int i = 0; i < 4; i++) {
    int idx = base + t * 4 + i;
    v[i] = (idx < N) ? deg[idx] : 0;
    s += v[i];
  }
  part[t] = s;
  __syncthreads();
  for (int off = 1; off < 256; off <<= 1) {
    int x = (t >= off) ? part[t - off] : 0;
    __syncthreads();
    part[t] += x;
    __syncthreads();
  }
  int run = part[t] - s;  // exclusive prefix within block
#pragma unroll
  for (int i = 0; i < 4; i++) {
    int idx = base + t * 4 + i;
    if (idx < N) rowptr[idx] = run;
    run += v[i];
  }
  if (t == 255) bsum[blockIdx.x] = part[255];
}

__global__ void k_scan2(int* __restrict__ bsum, int nb) {
  if (threadIdx.x == 0 && blockIdx.x == 0) {
    int run = 0;
    for (int i = 0; i < nb; i++) { int v = bsum[i]; bsum[i] = run; run += v; }
  }
}

__global__ void k_scan3(int* __restrict__ rowptr, const int* __restrict__ bsum,
                        int N, int E) {
  int i = blockIdx.x * blockDim.x + threadIdx.x;
  if (i < N) rowptr[i] += bsum[i >> 10];
  else if (i == N) rowptr[N] = E;
}

// ---------------------------------------------------------------------------
// CSR fill: col[rowptr[d] + slot] = src  (500k int atomics, L2-resident)
// ---------------------------------------------------------------------------
__global__ void k_fill(const int* __restrict__ src, const int* __restrict__ dst,
                       const int* __restrict__ rowptr, int* __restrict__ fill,
                       int* __restrict__ col, int E) {
  int e = blockIdx.x * blockDim.x + threadIdx.x;
  if (e >= E) return;
  int d = dst[e];
  int p = rowptr[d] + atomicAdd(&fill[d], 1);
  col[p] = src[e];
}

// ---------------------------------------------------------------------------
// SAGE1: x1 = relu(wl @ (sum1/deg) + wr @ pos + b) -> xcat[:,0:128]
// ---------------------------------------------------------------------------
__global__ void k_sage1(const float* __restrict__ sum1, const int* __restrict__ deg,
                        const float* __restrict__ pos,
                        const float* __restrict__ wl, const float* __restrict__ wr,
                        const float* __restrict__ b, float* __restrict__ xcat, int N) {
  int n = blockIdx.x;
  if (n >= N) return;
  int o = threadIdx.x;  // 0..127
  float c = fmaxf((float)deg[n], 1.f);
  float a0 = sum1[n * 3 + 0] / c, a1 = sum1[n * 3 + 1] / c, a2 = sum1[n * 3 + 2] / c;
  float p0 = pos[n * 3 + 0], p1 = pos[n * 3 + 1], p2 = pos[n * 3 + 2];
  float v = b[o] + wl[o * 3 + 0] * a0 + wl[o * 3 + 1] * a1 + wl[o * 3 + 2] * a2
                 + wr[o * 3 + 0] * p0 + wr[o * 3 + 1] * p1 + wr[o * 3 + 2] * p2;
  xcat[(size_t)n * 256 + o] = fmaxf(v, 0.f);
}

// ---------------------------------------------------------------------------
// Mean-aggregate x1 over incoming edges, CSR gather, wave per node.
// Fuses the /deg normalize. No atomics.
// ---------------------------------------------------------------------------
__global__ void k_agg_x1(const int* __restrict__ rowptr, const int* __restrict__ col,
                         const float* __restrict__ xcat, float* __restrict__ sum2, int N) {
  int w = (blockIdx.x * blockDim.x + threadIdx.x) >> 6;
  int nw = (gridDim.x * blockDim.x) >> 6;
  int lane = threadIdx.x & 63;
  for (int n = w; n < N; n += nw) {
    int k0 = rowptr[n], k1 = rowptr[n + 1];
    float2 acc = {0.f, 0.f};
    for (int k = k0; k < k1; k++) {
      int s = col[k];
      float2 v = *(const float2*)&xcat[(size_t)s * 256 + lane * 2];
      acc.x += v.x; acc.y += v.y;
    }
    float inv = 1.f / fmaxf((float)(k1 - k0), 1.f);
    acc.x *= inv; acc.y *= inv;
    *(float2*)&sum2[(size_t)n * 128 + lane * 2] = acc;
  }
}

// ---------------------------------------------------------------------------
// Generic tiled fp32 GEMM: C[n, co+m] = act( sum_k Acat(n,k)*W(m,k) + bias[m] )
// ---------------------------------------------------------------------------
#define GBM 128
#define GBN 64
#define GBK 16
__global__ __launch_bounds__(256) void gemm_cat(
    const float* __restrict__ A1, int as1, int K1,
    const float* __restrict__ A2, int as2, int K2,
    const float* __restrict__ W1, const float* __restrict__ W2,
    const float* __restrict__ bias, float* __restrict__ C, int cs, int co,
    int Nr, int M, int relu) {
  __shared__ float As[GBK][GBM + 4];
  __shared__ float Bs[GBK][GBN + 4];
  int tid = threadIdx.x;
  int bm = blockIdx.x, bn = blockIdx.y;
  int tx = tid & 15, ty = tid >> 4;
  int K = K1 + K2;

  float acc[8][4];
#pragma unroll
  for (int i = 0; i < 8; i++)
#pragma unroll
    for (int j = 0; j < 4; j++) acc[i][j] = 0.f;

  int kk = tid & 15;
  int rowg = tid >> 4;

  for (int kt = 0; kt < K; kt += GBK) {
    int kg = kt + kk;
    const float* Ap; int ast, kl;
    if (kg < K1) { Ap = A1; ast = as1; kl = kg; }
    else         { Ap = A2; ast = as2; kl = kg - K1; }
    const float* Wp; int wst, wk;
    if (kg < K1) { Wp = W1; wst = K1; wk = kg; }
    else         { Wp = W2; wst = K2; wk = kg - K1; }
#pragma unroll
    for (int t = 0; t < 8; t++) {
      int i = rowg + t * 16;
      int n = bm * GBM + i;
      As[kk][i] = (n < Nr) ? Ap[(size_t)n * ast + kl] : 0.f;
    }
#pragma unroll
    for (int t = 0; t < 4; t++) {
      int m = rowg + t * 16;
      int gm = bn * GBN + m;
      Bs[kk][m] = (gm < M) ? Wp[(size_t)gm * wst + wk] : 0.f;
    }
    __syncthreads();
#pragma unroll
    for (int k = 0; k < GBK; k++) {
      float4 a0 = *(const float4*)&As[k][ty * 8];
      float4 a1 = *(const float4*)&As[k][ty * 8 + 4];
      float4 b0 = *(const float4*)&Bs[k][tx * 4];
      float av[8] = {a0.x, a0.y, a0.z, a0.w, a1.x, a1.y, a1.z, a1.w};
      float bv[4] = {b0.x, b0.y, b0.z, b0.w};
#pragma unroll
      for (int i = 0; i < 8; i++)
#pragma unroll
        for (int j = 0; j < 4; j++) acc[i][j] += av[i] * bv[j];
    }
    __syncthreads();
  }

#pragma unroll
  for (int i = 0; i < 8; i++) {
    int n = bm * GBM + ty * 8 + i;
    if (n >= Nr) continue;
#pragma unroll
    for (int j = 0; j < 4; j++) {
      int gm = bn * GBN + tx * 4 + j;
      if (gm >= M) continue;
      float v = acc[i][j];
      if (bias) v += bias[gm];
      if (relu) v = fmaxf(v, 0.f);
      C[(size_t)n * cs + co + gm] = v;
    }
  }
}

// ---------------------------------------------------------------------------
// GAT attention coefficients (wave per node)
// attn layout: [n][0]=as0 [1]=as1 [2]=ad0 [3]=ad1
// ---------------------------------------------------------------------------
__global__ void k_attn(const float* __restrict__ xw, const float* __restrict__ asrc,
                       const float* __restrict__ adst, float* __restrict__ attn, int N) {
  int w = (blockIdx.x * blockDim.x + threadIdx.x) >> 6;
  int nw = (gridDim.x * blockDim.x) >> 6;
  int lane = threadIdx.x & 63;
  for (int n = w; n < N; n += nw) {
    float4 x = *(const float4*)&xw[(size_t)n * 256 + lane * 4];
    float4 a = *(const float4*)&asrc[lane * 4];
    float4 d = *(const float4*)&adst[lane * 4];
    float ps = x.x * a.x + x.y * a.y + x.z * a.z + x.w * a.w;
    float pd = x.x * d.x + x.y * d.y + x.z * d.z + x.w * d.w;
#pragma unroll
    for (int m = 16; m >= 1; m >>= 1) {
      ps += __shfl_xor(ps, m);
      pd += __shfl_xor(pd, m);
    }
    if (lane == 0)       { attn[n * 4 + 0] = ps; attn[n * 4 + 2] = pd; }
    else if (lane == 32) { attn[n * 4 + 1] = ps; attn[n * 4 + 3] = pd; }
  }
}

// ---------------------------------------------------------------------------
// GAT: CSR gather, wave per node. Softmax weights + weighted sum + denom all
// in registers; fuses self-loop, head-mean, /(deg+1), +g_b. No atomics.
// lanes 0..31 = head0 (ch 0..127), lanes 32..63 = head1 (ch 0..127).
// (softmax shift-invariance: skipping segment-max is mathematically identical)
// ---------------------------------------------------------------------------
__global__ void k_gat_gather(const int* __restrict__ rowptr, const int* __restrict__ col,
                             const float* __restrict__ xw, const float* __restrict__ attn,
                             const float* __restrict__ gb, float* __restrict__ x3g, int N) {
  int w = (blockIdx.x * blockDim.x + threadIdx.x) >> 6;
  int nw = (gridDim.x * blockDim.x) >> 6;
  int lane = threadIdx.x & 63;
  int h = lane >> 5;
  for (int n = w; n < N; n += nw) {
    int k0 = rowptr[n], k1 = rowptr[n + 1];
    float ad = attn[n * 4 + 2 + h];
    float4 acc = {0.f, 0.f, 0.f, 0.f};
    float den = 0.f;
    for (int k = k0; k < k1; k++) {
      int s = col[k];
      float ea = attn[s * 4 + h] + ad;
      float el = ea >= 0.f ? ea : 0.2f * ea;
      float wgt = expf(el);
      float4 xv = *(const float4*)&xw[(size_t)s * 256 + lane * 4];
      acc.x += wgt * xv.x; acc.y += wgt * xv.y;
      acc.z += wgt * xv.z; acc.w += wgt * xv.w;
      den += wgt;
    }
    // self-loop
    {
      float ea = attn[n * 4 + h] + ad;
      float el = ea >= 0.f ? ea : 0.2f * ea;
      float wgt = expf(el);
      float4 xv = *(const float4*)&xw[(size_t)n * 256 + lane * 4];
      acc.x += wgt * xv.x; acc.y += wgt * xv.y;
      acc.z += wgt * xv.z; acc.w += wgt * xv.w;
      den += wgt;
    }
    float invD = 1.f / den;
    float4 q = {acc.x * invD, acc.y * invD, acc.z * invD, acc.w * invD};
    float4 qx;
    qx.x = __shfl_xor(q.x, 32);
    qx.y = __shfl_xor(q.y, 32);
    qx.z = __shfl_xor(q.z, 32);
    qx.w = __shfl_xor(q.w, 32);
    if (lane < 32) {
      float invc = 1.f / (float)(k1 - k0 + 1);
      float4 g = *(const float4*)&gb[lane * 4];
      float4 r;
      r.x = 0.5f * (q.x + qx.x) * invc + g.x;
      r.y = 0.5f * (q.y + qx.y) * invc + g.y;
      r.z = 0.5f * (q.z + qx.z) * invc + g.z;
      r.w = 0.5f * (q.w + qx.w) * invc + g.w;
      *(float4*)&x3g[(size_t)n * 128 + lane * 4] = r;
    }
  }
}

// ---------------------------------------------------------------------------
// Global mean pool over sorted batch: run-length accumulate, flush on change
// ---------------------------------------------------------------------------
__global__ void k_pool(const float* __restrict__ x3g, const int* __restrict__ batch,
                       float* __restrict__ zsum, float* __restrict__ zcnt, int N) {
  int t = threadIdx.x;  // 0..127
  int chunk = (N + gridDim.x - 1) / gridDim.x;
  int n0 = blockIdx.x * chunk;
  int n1 = min(N, n0 + chunk);
  if (n0 >= n1) return;
  int cur = batch[n0];
  float acc = 0.f, cacc = 0.f;
  for (int n = n0; n < n1; n++) {
    int b = batch[n];
    if (b != cur) {
      atomicAdd(&zsum[cur * 128 + t], acc);
      if (t == 0) atomicAdd(&zcnt[cur], cacc);
      acc = 0.f; cacc = 0.f; cur = b;
    }
    acc += x3g[(size_t)n * 128 + t];
    cacc += 1.f;
  }
  atomicAdd(&zsum[cur * 128 + t], acc);
  if (t == 0) atomicAdd(&zcnt[cur], cacc);
}

__global__ void k_zmean(const float* __restrict__ zsum, const float* __restrict__ zcnt,
                        float* __restrict__ zmean, int Bn) {
  int i = blockIdx.x * blockDim.x + threadIdx.x;
  if (i >= Bn * 128) return;
  int b = i >> 7;
  zmean[i] = zsum[i] / fmaxf(zcnt[b], 1.f);
}

// ---------------------------------------------------------------------------
// Decoder layer: Y = BN(X @ W.T + b) [relu], single block of 256 threads.
// ---------------------------------------------------------------------------
__global__ void dec_layer(const float* __restrict__ X, float* __restrict__ Y,
                          const float* __restrict__ W, const float* __restrict__ bias,
                          const float* __restrict__ g, const float* __restrict__ beta,
                          int Ki, int Mo, int Bn, int relu,
                          float* __restrict__ out, float* __restrict__ argout) {
  int tid = threadIdx.x;
  for (int o = tid; o < Bn * Mo; o += blockDim.x) {
    int r = o / Mo, m = o - r * Mo;
    float acc = bias[m];
    const float* xr = &X[(size_t)r * Ki];
    const float* wr = &W[(size_t)m * Ki];
    for (int k = 0; k < Ki; k += 4) {
      float4 xv = *(const float4*)&xr[k];
      float4 wv = *(const float4*)&wr[k];
      acc += xv.x * wv.x + xv.y * wv.y + xv.z * wv.z + xv.w * wv.w;
    }
    Y[o] = acc;
  }
  __syncthreads();
  for (int m = tid; m < Mo; m += blockDim.x) {
    float mean = 0.f;
    for (int r = 0; r < Bn; r++) mean += Y[r * Mo + m];
    mean /= (float)Bn;
    float var = 0.f;
    for (int r = 0; r < Bn; r++) {
      float dv = Y[r * Mo + m] - mean;
      var += dv * dv;
    }
    var /= (float)Bn;
    float sc = g[m] / sqrtf(var + BN_EPS);
    float sh = beta[m] - mean * sc;
    for (int r = 0; r < Bn; r++) {
      float v = Y[r * Mo + m] * sc + sh;
      if (relu) v = fmaxf(v, 0.f);
      Y[r * Mo + m] = v;
      if (out) out[r * Mo + m] = v;
    }
  }
  if (argout) {
    __syncthreads();
    if (tid < Bn) {
      const float* yr = &Y[tid * Mo];
      float best = yr[0];
      int bi = 0;
      for (int j = 1; j < Mo; j++)
        if (yr[j] > best) { best = yr[j]; bi = j; }
      argout[tid] = (float)bi;
    }
  }
}

// ---------------------------------------------------------------------------
extern "C" void kernel_launch(void* const* d_in, const int* in_sizes, int n_in,
                              void* d_out, int out_size, void* d_ws, size_t ws_size,
                              hipStream_t stream) {
  const int N = in_sizes[0] / 3;
  const int E = in_sizes[1] / 2;
  const int Bn = out_size / 41;  // z [B,40] + argmax [B]

  const float* pos = (const float*)d_in[0];
  const int* ei = (const int*)d_in[1];
  const int* src = ei;
  const int* dst = ei + E;
  const int* batch = (const int*)d_in[2];
  const float* s1_wl = (const float*)d_in[3];
  const float* s1_wr = (const float*)d_in[4];
  const float* s1_b  = (const float*)d_in[5];
  const float* s2_wl = (const float*)d_in[6];
  const float* s2_wr = (const float*)d_in[7];
  const float* s2_b  = (const float*)d_in[8];
  const float* g_w    = (const float*)d_in[9];
  const float* g_asrc = (const float*)d_in[10];
  const float* g_adst = (const float*)d_in[11];
  const float* g_b    = (const float*)d_in[12];
  const float* d1_w = (const float*)d_in[13];
  const float* d1_b = (const float*)d_in[14];
  const float* bn1_g = (const float*)d_in[15];
  const float* bn1_b = (const float*)d_in[16];
  const float* d2_w = (const float*)d_in[17];
  const float* d2_b = (const float*)d_in[18];
  const float* bn2_g = (const float*)d_in[19];
  const float* bn2_b = (const float*)d_in[20];
  const float* d3_w = (const float*)d_in[21];
  const float* d3_b = (const float*)d_in[22];
  const float* bn3_g = (const float*)d_in[23];
  const float* bn3_b = (const float*)d_in[24];

  size_t Ns = (size_t)N;
  // int region: deg | fill | rowptr(N+1) | col(E)
  int* ip = (int*)d_ws;
  int* deg    = ip;
  int* fill   = ip + Ns;
  int* rowptr = ip + 2 * Ns;
  int* col    = ip + 3 * Ns + 1;
  size_t intCount = (3 * Ns + 1 + (size_t)E + 3) & ~(size_t)3;

  float* w = (float*)d_ws + intCount;
  float* sum1  = w;               // 3N
  float* bsum  = (float*)(ip + 3 * Ns + 1 + (size_t)E);  // unused alias
  int*   bsums = (int*)(w + 3 * Ns);  // scan block sums (reuse: 128 ints) -- careful: place separately
  float* xcat  = w + 4 * Ns;      // 256N  (x1|x2)
  float* sum2  = w + 260 * Ns;    // 128N  (mean agg; later x3gat)
  float* xw    = w + 388 * Ns;    // 256N
  float* attn  = w + 644 * Ns;    // 4N
  float* base  = w + 648 * Ns;
  float* zsum  = base;            // Bn*128
  float* zcnt  = base + 8192;     // Bn
  float* zmean = base + 8256;     // Bn*128
  float* db1   = base + 16448;    // Bn*256
  float* db2   = db1 + 16384;     // Bn*128
  float* db3   = db2 + 8192;      // Bn*40
  float* out = (float*)d_out;
  (void)bsum;

  // zero: deg+fill (int), sum1, pool accumulators
  hipMemsetAsync(ip, 0, 2 * Ns * sizeof(int), stream);
  hipMemsetAsync(sum1, 0, 3 * Ns * sizeof(float), stream);
  hipMemsetAsync(zsum, 0, (8192 + 64) * sizeof(float), stream);

  k_deg_sum1<<<(E + 255) / 256, 256, 0, stream>>>(src, dst, pos, deg, sum1, E);

  // CSR build
  int nb = (N + 1023) / 1024;
  k_scan1<<<nb, 256, 0, stream>>>(deg, rowptr, bsums, N);
  k_scan2<<<1, 64, 0, stream>>>(bsums, nb);
  k_scan3<<<(N + 256) / 256, 256, 0, stream>>>(rowptr, bsums, N, E);
  k_fill<<<(E + 255) / 256, 256, 0, stream>>>(src, dst, rowptr, fill, col, E);

  k_sage1<<<N, 128, 0, stream>>>(sum1, deg, pos, s1_wl, s1_wr, s1_b, xcat, N);
  k_agg_x1<<<1024, 256, 0, stream>>>(rowptr, col, xcat, sum2, N);

  // SAGE2: x2 = relu([m|x1] @ [wl|wr].T + b) -> xcat[:,128:256]
  dim3 g2((N + GBM - 1) / GBM, 128 / GBN);
  gemm_cat<<<g2, 256, 0, stream>>>(sum2, 128, 128, xcat, 256, 128,
                                   s2_wl, s2_wr, s2_b, xcat, 256, 128, N, 128, 1);

  // GAT projection: xw = xcat @ g_w.T
  dim3 g3((N + GBM - 1) / GBM, 256 / GBN);
  gemm_cat<<<g3, 256, 0, stream>>>(xcat, 256, 256, nullptr, 0, 0,
                                   g_w, nullptr, nullptr, xw, 256, 0, N, 256, 0);

  k_attn<<<(N + 3) / 4, 256, 0, stream>>>(xw, g_asrc, g_adst, attn, N);
  k_gat_gather<<<2048, 256, 0, stream>>>(rowptr, col, xw, attn, g_b, sum2, N);

  k_pool<<<128, 128, 0, stream>>>(sum2, batch, zsum, zcnt, N);
  k_zmean<<<(Bn * 128 + 255) / 256, 256, 0, stream>>>(zsum, zcnt, zmean, Bn);

  dec_layer<<<1, 256, 0, stream>>>(zmean, db1, d1_w, d1_b, bn1_g, bn1_b,
                                   128, 256, Bn, 1, nullptr, nullptr);
  dec_layer<<<1, 256, 0, stream>>>(db1, db2, d2_w, d2_b, bn2_g, bn2_b,
                                   256, 128, Bn, 1, nullptr, nullptr);
  dec_layer<<<1, 256, 0, stream>>>(db2, db3, d3_w, d3_b, bn3_g, bn3_b,
                                   128, 40, Bn, 0, out, out + Bn * 40);
}

// Round 4
// 772.849 us; speedup vs baseline: 5.2568x; 2.7055x over previous
//
#include <hip/hip_runtime.h>
#include <math.h>

#define BN_EPS 1e-5f

typedef __attribute__((ext_vector_type(8))) short short8;
typedef __attribute__((ext_vector_type(4))) float f32x4;

__device__ __forceinline__ float bf2f(unsigned short u) {
  return __builtin_bit_cast(float, ((unsigned)u) << 16);
}
__device__ __forceinline__ unsigned short f2bf(float f) {
  unsigned u = __builtin_bit_cast(unsigned, f);
  unsigned r = (u + 0x7fffu + ((u >> 16) & 1u)) >> 16;
  return (unsigned short)r;
}
// split fp32 -> (hi, lo) bf16 pair; hi+lo reproduces x to ~2^-18 rel
__device__ __forceinline__ void fsplit(float x, unsigned short& h, unsigned short& l) {
  h = f2bf(x);
  l = f2bf(x - bf2f(h));
}

// ---------------------------------------------------------------------------
// Edge pass 1: int in-degree + scatter-sum of pos[src] into sum1[dst]
// ---------------------------------------------------------------------------
__global__ void k_deg_sum1(const int* __restrict__ src, const int* __restrict__ dst,
                           const float* __restrict__ pos, int* __restrict__ deg,
                           float* __restrict__ sum1, int E) {
  int e = blockIdx.x * blockDim.x + threadIdx.x;
  if (e >= E) return;
  int s = src[e], d = dst[e];
  atomicAdd(&deg[d], 1);
  atomicAdd(&sum1[d * 3 + 0], pos[s * 3 + 0]);
  atomicAdd(&sum1[d * 3 + 1], pos[s * 3 + 1]);
  atomicAdd(&sum1[d * 3 + 2], pos[s * 3 + 2]);
}

// ---------------------------------------------------------------------------
// Exclusive scan of deg -> rowptr
// ---------------------------------------------------------------------------
__global__ void k_scan1(const int* __restrict__ deg, int* __restrict__ rowptr,
                        int* __restrict__ bsum, int N) {
  __shared__ int part[256];
  int t = threadIdx.x;
  int base = blockIdx.x * 1024;
  int v[4]; int s = 0;
#pragma unroll
  for (int i = 0; i < 4; i++) {
    int idx = base + t * 4 + i;
    v[i] = (idx < N) ? deg[idx] : 0;
    s += v[i];
  }
  part[t] = s;
  __syncthreads();
  for (int off = 1; off < 256; off <<= 1) {
    int x = (t >= off) ? part[t - off] : 0;
    __syncthreads();
    part[t] += x;
    __syncthreads();
  }
  int run = part[t] - s;
#pragma unroll
  for (int i = 0; i < 4; i++) {
    int idx = base + t * 4 + i;
    if (idx < N) rowptr[idx] = run;
    run += v[i];
  }
  if (t == 255) bsum[blockIdx.x] = part[255];
}

__global__ void k_scan2(int* __restrict__ bsum, int nb) {
  if (threadIdx.x == 0 && blockIdx.x == 0) {
    int run = 0;
    for (int i = 0; i < nb; i++) { int v = bsum[i]; bsum[i] = run; run += v; }
  }
}

__global__ void k_scan3(int* __restrict__ rowptr, const int* __restrict__ bsum,
                        int N, int E) {
  int i = blockIdx.x * blockDim.x + threadIdx.x;
  if (i < N) rowptr[i] += bsum[i >> 10];
  else if (i == N) rowptr[N] = E;
}

__global__ void k_fill(const int* __restrict__ src, const int* __restrict__ dst,
                       const int* __restrict__ rowptr, int* __restrict__ fill,
                       int* __restrict__ col, int E) {
  int e = blockIdx.x * blockDim.x + threadIdx.x;
  if (e >= E) return;
  int d = dst[e];
  int p = rowptr[d] + atomicAdd(&fill[d], 1);
  col[p] = src[e];
}

// ---------------------------------------------------------------------------
// SAGE1: x1 = relu(wl @ (sum1/deg) + wr @ pos + b) -> catH/catL[:,0:128]
// ---------------------------------------------------------------------------
__global__ void k_sage1(const float* __restrict__ sum1, const int* __restrict__ deg,
                        const float* __restrict__ pos,
                        const float* __restrict__ wl, const float* __restrict__ wr,
                        const float* __restrict__ b,
                        unsigned short* __restrict__ catH, unsigned short* __restrict__ catL,
                        int N) {
  int n = blockIdx.x;
  if (n >= N) return;
  int o = threadIdx.x;  // 0..127
  float c = fmaxf((float)deg[n], 1.f);
  float a0 = sum1[n * 3 + 0] / c, a1 = sum1[n * 3 + 1] / c, a2 = sum1[n * 3 + 2] / c;
  float p0 = pos[n * 3 + 0], p1 = pos[n * 3 + 1], p2 = pos[n * 3 + 2];
  float v = b[o] + wl[o * 3 + 0] * a0 + wl[o * 3 + 1] * a1 + wl[o * 3 + 2] * a2
                 + wr[o * 3 + 0] * p0 + wr[o * 3 + 1] * p1 + wr[o * 3 + 2] * p2;
  v = fmaxf(v, 0.f);
  unsigned short h, l;
  fsplit(v, h, l);
  catH[(size_t)n * 256 + o] = h;
  catL[(size_t)n * 256 + o] = l;
}

// ---------------------------------------------------------------------------
// Mean-aggregate x1 over incoming edges (hi/lo reconstruct), wave per node.
// Writes hi/lo of the mean. No atomics.
// ---------------------------------------------------------------------------
__global__ void k_agg_x1(const int* __restrict__ rowptr, const int* __restrict__ col,
                         const unsigned short* __restrict__ catH,
                         const unsigned short* __restrict__ catL,
                         unsigned short* __restrict__ aggH,
                         unsigned short* __restrict__ aggL, int N) {
  int w = (blockIdx.x * blockDim.x + threadIdx.x) >> 6;
  int nw = (gridDim.x * blockDim.x) >> 6;
  int lane = threadIdx.x & 63;
  for (int n = w; n < N; n += nw) {
    int k0 = rowptr[n], k1 = rowptr[n + 1];
    float ax = 0.f, ay = 0.f;
    for (int k = k0; k < k1; k++) {
      int s = col[k];
      size_t base = (size_t)s * 256 + lane * 2;
      ushort2 vh = *(const ushort2*)&catH[base];
      ushort2 vl = *(const ushort2*)&catL[base];
      ax += bf2f(vh.x) + bf2f(vl.x);
      ay += bf2f(vh.y) + bf2f(vl.y);
    }
    float inv = 1.f / fmaxf((float)(k1 - k0), 1.f);
    unsigned short hx, lx, hy, ly;
    fsplit(ax * inv, hx, lx);
    fsplit(ay * inv, hy, ly);
    *(ushort2*)&aggH[(size_t)n * 128 + lane * 2] = make_ushort2(hx, hy);
    *(ushort2*)&aggL[(size_t)n * 128 + lane * 2] = make_ushort2(lx, ly);
  }
}

// ---------------------------------------------------------------------------
// Cast/concat fp32 weights -> bf16 hi/lo: k<K1 from a, else from b
// ---------------------------------------------------------------------------
__global__ void k_castcat(const float* __restrict__ a, const float* __restrict__ b,
                          unsigned short* __restrict__ oH, unsigned short* __restrict__ oL,
                          int K1, int K2, int M) {
  int i = blockIdx.x * blockDim.x + threadIdx.x;
  int K = K1 + K2;
  if (i >= M * K) return;
  int m = i / K, k = i - m * K;
  float v = (k < K1) ? a[m * K1 + k] : b[m * K2 + (k - K1)];
  unsigned short h, l;
  fsplit(v, h, l);
  oH[i] = h;
  oL[i] = l;
}

// ---------------------------------------------------------------------------
// Split-bf16 MFMA GEMM (fp32-equivalent): C = act(A . W^T + bias), where
// A = Ah+Al, W = Wh+Wl; A.W ~= AhWh + AhWl + AlWh (3 MFMAs / frag pair).
// A row-major (two K-chunks), W row-major [M,K]. Tile 128x128, BK=64,
// 4 waves x (32 rows x 128 cols) via mfma_f32_16x16x32_bf16.
// Output written as hi/lo bf16 pair.
// ---------------------------------------------------------------------------
__global__ __launch_bounds__(256) void gemm_split(
    const unsigned short* __restrict__ AH1, const unsigned short* __restrict__ AL1,
    int as1, int K1,
    const unsigned short* __restrict__ AH2, const unsigned short* __restrict__ AL2,
    int as2,
    const unsigned short* __restrict__ WH, const unsigned short* __restrict__ WL,
    const float* __restrict__ bias,
    unsigned short* __restrict__ CH, unsigned short* __restrict__ CL,
    int cs, int co, int Nr, int K, int relu) {
  __shared__ unsigned short AsH[128][72];  // 144B row stride: odd multiple of 16B
  __shared__ unsigned short AsL[128][72];
  __shared__ unsigned short BsH[128][72];
  __shared__ unsigned short BsL[128][72];
  int tid = threadIdx.x;
  int bm = blockIdx.x, bn = blockIdx.y;
  int wv = tid >> 6, L = tid & 63;
  int m16 = L & 15, quad = L >> 4;
  int rbase = wv * 32;

  f32x4 acc[2][8];
#pragma unroll
  for (int i = 0; i < 2; i++)
#pragma unroll
    for (int j = 0; j < 8; j++) acc[i][j] = (f32x4){0.f, 0.f, 0.f, 0.f};

  for (int kt = 0; kt < K; kt += 64) {
    const unsigned short *ApH, *ApL;
    int ast, kl;
    if (kt < K1) { ApH = AH1; ApL = AL1; ast = as1; kl = kt; }
    else         { ApH = AH2; ApL = AL2; ast = as2; kl = kt - K1; }
#pragma unroll
    for (int i = 0; i < 4; i++) {
      int flat = tid * 4 + i;           // 0..1023
      int row = flat >> 3;              // 0..127
      int kc = (flat & 7) * 8;          // 0..56
      int rg = bm * 128 + row;
      uint4 vah = {0u, 0u, 0u, 0u}, val = {0u, 0u, 0u, 0u};
      if (rg < Nr) {
        size_t a = (size_t)rg * ast + kl + kc;
        vah = *(const uint4*)&ApH[a];
        val = *(const uint4*)&ApL[a];
      }
      *(uint4*)&AsH[row][kc] = vah;
      *(uint4*)&AsL[row][kc] = val;
      int ng = bn * 128 + row;
      size_t wb = (size_t)ng * K + kt + kc;
      *(uint4*)&BsH[row][kc] = *(const uint4*)&WH[wb];
      *(uint4*)&BsL[row][kc] = *(const uint4*)&WL[wb];
    }
    __syncthreads();
#pragma unroll
    for (int ks = 0; ks < 2; ks++) {
      short8 afH[2], afL[2];
#pragma unroll
      for (int rt = 0; rt < 2; rt++) {
        afH[rt] = *(const short8*)&AsH[rbase + rt * 16 + m16][ks * 32 + quad * 8];
        afL[rt] = *(const short8*)&AsL[rbase + rt * 16 + m16][ks * 32 + quad * 8];
      }
#pragma unroll
      for (int ct = 0; ct < 8; ct++) {
        short8 bfH = *(const short8*)&BsH[ct * 16 + m16][ks * 32 + quad * 8];
        short8 bfL = *(const short8*)&BsL[ct * 16 + m16][ks * 32 + quad * 8];
#pragma unroll
        for (int rt = 0; rt < 2; rt++) {
          acc[rt][ct] = __builtin_amdgcn_mfma_f32_16x16x32_bf16(afH[rt], bfH, acc[rt][ct], 0, 0, 0);
          acc[rt][ct] = __builtin_amdgcn_mfma_f32_16x16x32_bf16(afH[rt], bfL, acc[rt][ct], 0, 0, 0);
          acc[rt][ct] = __builtin_amdgcn_mfma_f32_16x16x32_bf16(afL[rt], bfH, acc[rt][ct], 0, 0, 0);
        }
      }
    }
    __syncthreads();
  }

  // epilogue: C/D layout col=lane&15, row=quad*4+reg
#pragma unroll
  for (int rt = 0; rt < 2; rt++) {
#pragma unroll
    for (int r = 0; r < 4; r++) {
      int rg = bm * 128 + rbase + rt * 16 + quad * 4 + r;
      if (rg >= Nr) continue;
#pragma unroll
      for (int ct = 0; ct < 8; ct++) {
        int cg = bn * 128 + ct * 16 + m16;
        float v = acc[rt][ct][r];
        if (bias) v += bias[cg];
        if (relu) v = fmaxf(v, 0.f);
        unsigned short h, l;
        fsplit(v, h, l);
        size_t o = (size_t)rg * cs + co + cg;
        CH[o] = h;
        CL[o] = l;
      }
    }
  }
}

// ---------------------------------------------------------------------------
// GAT attention coefficients from hi/lo xw (wave per node)
// attn layout: [n][0]=as0 [1]=as1 [2]=ad0 [3]=ad1
// ---------------------------------------------------------------------------
__global__ void k_attn(const unsigned short* __restrict__ xwH,
                       const unsigned short* __restrict__ xwL,
                       const float* __restrict__ asrc,
                       const float* __restrict__ adst, float* __restrict__ attn, int N) {
  int w = (blockIdx.x * blockDim.x + threadIdx.x) >> 6;
  int nw = (gridDim.x * blockDim.x) >> 6;
  int lane = threadIdx.x & 63;
  for (int n = w; n < N; n += nw) {
    size_t base = (size_t)n * 256 + lane * 4;
    ushort4 xh = *(const ushort4*)&xwH[base];
    ushort4 xl = *(const ushort4*)&xwL[base];
    float x0 = bf2f(xh.x) + bf2f(xl.x), x1 = bf2f(xh.y) + bf2f(xl.y);
    float x2 = bf2f(xh.z) + bf2f(xl.z), x3 = bf2f(xh.w) + bf2f(xl.w);
    float4 a = *(const float4*)&asrc[lane * 4];
    float4 d = *(const float4*)&adst[lane * 4];
    float ps = x0 * a.x + x1 * a.y + x2 * a.z + x3 * a.w;
    float pd = x0 * d.x + x1 * d.y + x2 * d.z + x3 * d.w;
#pragma unroll
    for (int m = 16; m >= 1; m >>= 1) {
      ps += __shfl_xor(ps, m);
      pd += __shfl_xor(pd, m);
    }
    if (lane == 0)       { attn[n * 4 + 0] = ps; attn[n * 4 + 2] = pd; }
    else if (lane == 32) { attn[n * 4 + 1] = ps; attn[n * 4 + 3] = pd; }
  }
}

// ---------------------------------------------------------------------------
// GAT: CSR gather over hi/lo xw, wave per node, all state in registers.
// lanes 0..31 = head0 (ch 0..127), lanes 32..63 = head1 (ch 0..127).
// (softmax shift-invariance: skipping segment-max is mathematically identical)
// ---------------------------------------------------------------------------
__global__ void k_gat_gather(const int* __restrict__ rowptr, const int* __restrict__ col,
                             const unsigned short* __restrict__ xwH,
                             const unsigned short* __restrict__ xwL,
                             const float* __restrict__ attn,
                             const float* __restrict__ gb, float* __restrict__ x3g, int N) {
  int w = (blockIdx.x * blockDim.x + threadIdx.x) >> 6;
  int nw = (gridDim.x * blockDim.x) >> 6;
  int lane = threadIdx.x & 63;
  int h = lane >> 5;
  for (int n = w; n < N; n += nw) {
    int k0 = rowptr[n], k1 = rowptr[n + 1];
    float ad = attn[n * 4 + 2 + h];
    float a0 = 0.f, a1 = 0.f, a2 = 0.f, a3 = 0.f, den = 0.f;
    for (int k = k0; k < k1; k++) {
      int s = col[k];
      float ea = attn[s * 4 + h] + ad;
      float el = ea >= 0.f ? ea : 0.2f * ea;
      float wgt = expf(el);
      size_t base = (size_t)s * 256 + lane * 4;
      ushort4 xh = *(const ushort4*)&xwH[base];
      ushort4 xl = *(const ushort4*)&xwL[base];
      a0 += wgt * (bf2f(xh.x) + bf2f(xl.x));
      a1 += wgt * (bf2f(xh.y) + bf2f(xl.y));
      a2 += wgt * (bf2f(xh.z) + bf2f(xl.z));
      a3 += wgt * (bf2f(xh.w) + bf2f(xl.w));
      den += wgt;
    }
    {  // self-loop
      float ea = attn[n * 4 + h] + ad;
      float el = ea >= 0.f ? ea : 0.2f * ea;
      float wgt = expf(el);
      size_t base = (size_t)n * 256 + lane * 4;
      ushort4 xh = *(const ushort4*)&xwH[base];
      ushort4 xl = *(const ushort4*)&xwL[base];
      a0 += wgt * (bf2f(xh.x) + bf2f(xl.x));
      a1 += wgt * (bf2f(xh.y) + bf2f(xl.y));
      a2 += wgt * (bf2f(xh.z) + bf2f(xl.z));
      a3 += wgt * (bf2f(xh.w) + bf2f(xl.w));
      den += wgt;
    }
    float invD = 1.f / den;
    float q0 = a0 * invD, q1 = a1 * invD, q2 = a2 * invD, q3 = a3 * invD;
    float p0 = __shfl_xor(q0, 32), p1 = __shfl_xor(q1, 32);
    float p2 = __shfl_xor(q2, 32), p3 = __shfl_xor(q3, 32);
    if (lane < 32) {
      float invc = 1.f / (float)(k1 - k0 + 1);
      float4 g = *(const float4*)&gb[lane * 4];
      float4 r;
      r.x = 0.5f * (q0 + p0) * invc + g.x;
      r.y = 0.5f * (q1 + p1) * invc + g.y;
      r.z = 0.5f * (q2 + p2) * invc + g.z;
      r.w = 0.5f * (q3 + p3) * invc + g.w;
      *(float4*)&x3g[(size_t)n * 128 + lane * 4] = r;
    }
  }
}

// ---------------------------------------------------------------------------
// Global mean pool over sorted batch: run-length accumulate, flush on change
// ---------------------------------------------------------------------------
__global__ void k_pool(const float* __restrict__ x3g, const int* __restrict__ batch,
                       float* __restrict__ zsum, float* __restrict__ zcnt, int N) {
  int t = threadIdx.x;  // 0..127
  int chunk = (N + gridDim.x - 1) / gridDim.x;
  int n0 = blockIdx.x * chunk;
  int n1 = min(N, n0 + chunk);
  if (n0 >= n1) return;
  int cur = batch[n0];
  float acc = 0.f, cacc = 0.f;
  for (int n = n0; n < n1; n++) {
    int b = batch[n];
    if (b != cur) {
      atomicAdd(&zsum[cur * 128 + t], acc);
      if (t == 0) atomicAdd(&zcnt[cur], cacc);
      acc = 0.f; cacc = 0.f; cur = b;
    }
    acc += x3g[(size_t)n * 128 + t];
    cacc += 1.f;
  }
  atomicAdd(&zsum[cur * 128 + t], acc);
  if (t == 0) atomicAdd(&zcnt[cur], cacc);
}

__global__ void k_zmean(const float* __restrict__ zsum, const float* __restrict__ zcnt,
                        float* __restrict__ zmean, int Bn) {
  int i = blockIdx.x * blockDim.x + threadIdx.x;
  if (i >= Bn * 128) return;
  int b = i >> 7;
  zmean[i] = zsum[i] / fmaxf(zcnt[b], 1.f);
}

// ---------------------------------------------------------------------------
// Decoder layer, column-parallel: one block (1 wave, Bn=64 threads) per output
// column. Thread r = batch row. BN mean/var via wave shuffle. All fp32.
// ---------------------------------------------------------------------------
__global__ void dec_col(const float* __restrict__ X, float* __restrict__ Y,
                        const float* __restrict__ W, const float* __restrict__ bias,
                        const float* __restrict__ g, const float* __restrict__ beta,
                        int Ki, int Mo, int Bn, int relu) {
  int m = blockIdx.x;
  int r = threadIdx.x;  // 0..Bn-1 (Bn==64)
  float acc = bias[m];
  const float* xr = &X[(size_t)r * Ki];
  const float* wr = &W[(size_t)m * Ki];
  for (int k = 0; k < Ki; k += 4) {
    float4 xv = *(const float4*)&xr[k];
    float4 wv = *(const float4*)&wr[k];
    acc += xv.x * wv.x + xv.y * wv.y + xv.z * wv.z + xv.w * wv.w;
  }
  float s = acc;
#pragma unroll
  for (int o = 32; o >= 1; o >>= 1) s += __shfl_xor(s, o);
  float mean = s / (float)Bn;
  float d = acc - mean;
  float v2 = d * d;
#pragma unroll
  for (int o = 32; o >= 1; o >>= 1) v2 += __shfl_xor(v2, o);
  float var = v2 / (float)Bn;
  float y = g[m] * d / sqrtf(var + BN_EPS) + beta[m];
  if (relu) y = fmaxf(y, 0.f);
  Y[(size_t)r * Mo + m] = y;
}

__global__ void k_argmax(const float* __restrict__ z, float* __restrict__ argout,
                         int Bn, int Mo) {
  int r = blockIdx.x * blockDim.x + threadIdx.x;
  if (r >= Bn) return;
  const float* yr = &z[(size_t)r * Mo];
  float best = yr[0];
  int bi = 0;
  for (int j = 1; j < Mo; j++)
    if (yr[j] > best) { best = yr[j]; bi = j; }
  argout[r] = (float)bi;
}

// ---------------------------------------------------------------------------
extern "C" void kernel_launch(void* const* d_in, const int* in_sizes, int n_in,
                              void* d_out, int out_size, void* d_ws, size_t ws_size,
                              hipStream_t stream) {
  const int N = in_sizes[0] / 3;
  const int E = in_sizes[1] / 2;
  const int Bn = out_size / 41;  // z [B,40] + argmax [B]

  const float* pos = (const float*)d_in[0];
  const int* ei = (const int*)d_in[1];
  const int* src = ei;
  const int* dst = ei + E;
  const int* batch = (const int*)d_in[2];
  const float* s1_wl = (const float*)d_in[3];
  const float* s1_wr = (const float*)d_in[4];
  const float* s1_b  = (const float*)d_in[5];
  const float* s2_wl = (const float*)d_in[6];
  const float* s2_wr = (const float*)d_in[7];
  const float* s2_b  = (const float*)d_in[8];
  const float* g_w    = (const float*)d_in[9];
  const float* g_asrc = (const float*)d_in[10];
  const float* g_adst = (const float*)d_in[11];
  const float* g_b    = (const float*)d_in[12];
  const float* d1_w = (const float*)d_in[13];
  const float* d1_b = (const float*)d_in[14];
  const float* bn1_g = (const float*)d_in[15];
  const float* bn1_b = (const float*)d_in[16];
  const float* d2_w = (const float*)d_in[17];
  const float* d2_b = (const float*)d_in[18];
  const float* bn2_g = (const float*)d_in[19];
  const float* bn2_b = (const float*)d_in[20];
  const float* d3_w = (const float*)d_in[21];
  const float* d3_b = (const float*)d_in[22];
  const float* bn3_g = (const float*)d_in[23];
  const float* bn3_b = (const float*)d_in[24];

  size_t Ns = (size_t)N, Es = (size_t)E;
  char* p = (char*)d_ws;
  auto take = [&](size_t bytes) -> char* {
    char* r = p;
    p += (bytes + 255) & ~(size_t)255;
    return r;
  };
  int* deg    = (int*)take(Ns * 4);
  int* fillc  = (int*)take(Ns * 4);
  int* rowptr = (int*)take((Ns + 1) * 4);
  int* bsums  = (int*)take(1024);
  int* col    = (int*)take(Es * 4);
  float* sum1 = (float*)take(3 * Ns * 4);
  float* attn = (float*)take(4 * Ns * 4);
  unsigned short* catH = (unsigned short*)take(256 * Ns * 2);  // [x1|x2] hi
  unsigned short* catL = (unsigned short*)take(256 * Ns * 2);  // [x1|x2] lo
  unsigned short* aggH = (unsigned short*)take(128 * Ns * 2);  // mean-agg hi
  unsigned short* aggL = (unsigned short*)take(128 * Ns * 2);  // mean-agg lo
  unsigned short* xwH  = (unsigned short*)take(256 * Ns * 2);  // GAT proj hi
  unsigned short* xwL  = (unsigned short*)take(256 * Ns * 2);  // GAT proj lo
  unsigned short* wcH  = (unsigned short*)take(128 * 256 * 2); // [s2_wl|s2_wr] hi
  unsigned short* wcL  = (unsigned short*)take(128 * 256 * 2);
  unsigned short* gwH  = (unsigned short*)take(256 * 256 * 2); // g_w hi
  unsigned short* gwL  = (unsigned short*)take(256 * 256 * 2);
  float* zsum  = (float*)take(8192 * 4);
  float* zcnt  = (float*)take(256 * 4);
  float* zmean = (float*)take(8192 * 4);
  float* db1   = (float*)take(16384 * 4);
  float* db2   = (float*)take(8192 * 4);
  // x3g reuses the agg hi/lo region (agg dead after GEMM1): 128N fp32 = 2*128N bf16
  float* x3g = (float*)aggH;
  float* out = (float*)d_out;

  hipMemsetAsync(deg, 0, Ns * 4, stream);
  hipMemsetAsync(fillc, 0, Ns * 4, stream);
  hipMemsetAsync(sum1, 0, 3 * Ns * 4, stream);
  hipMemsetAsync(zsum, 0, 8192 * 4, stream);
  hipMemsetAsync(zcnt, 0, 256 * 4, stream);

  k_deg_sum1<<<(E + 255) / 256, 256, 0, stream>>>(src, dst, pos, deg, sum1, E);

  int nb = (N + 1023) / 1024;
  k_scan1<<<nb, 256, 0, stream>>>(deg, rowptr, bsums, N);
  k_scan2<<<1, 64, 0, stream>>>(bsums, nb);
  k_scan3<<<(N + 256) / 256, 256, 0, stream>>>(rowptr, bsums, N, E);
  k_fill<<<(E + 255) / 256, 256, 0, stream>>>(src, dst, rowptr, fillc, col, E);

  // weight casts (independent)
  k_castcat<<<(128 * 256 + 255) / 256, 256, 0, stream>>>(s2_wl, s2_wr, wcH, wcL, 128, 128, 128);
  k_castcat<<<(256 * 256 + 255) / 256, 256, 0, stream>>>(g_w, nullptr, gwH, gwL, 256, 0, 256);

  k_sage1<<<N, 128, 0, stream>>>(sum1, deg, pos, s1_wl, s1_wr, s1_b, catH, catL, N);
  k_agg_x1<<<2048, 256, 0, stream>>>(rowptr, col, catH, catL, aggH, aggL, N);

  // SAGE2: x2 = relu([agg|x1] @ [wl|wr].T + b) -> cat[:,128:256]
  dim3 g2((N + 127) / 128, 1);
  gemm_split<<<g2, 256, 0, stream>>>(aggH, aggL, 128, 128, catH, catL, 256,
                                     wcH, wcL, s2_b, catH, catL, 256, 128, N, 256, 1);

  // GAT projection: xw = [x1|x2] @ g_w.T -> xwH/xwL
  dim3 g3((N + 127) / 128, 2);
  gemm_split<<<g3, 256, 0, stream>>>(catH, catL, 256, 256, nullptr, nullptr, 0,
                                     gwH, gwL, nullptr, xwH, xwL, 256, 0, N, 256, 0);

  k_attn<<<(N + 3) / 4, 256, 0, stream>>>(xwH, xwL, g_asrc, g_adst, attn, N);
  k_gat_gather<<<2048, 256, 0, stream>>>(rowptr, col, xwH, xwL, attn, g_b, x3g, N);

  k_pool<<<256, 128, 0, stream>>>(x3g, batch, zsum, zcnt, N);
  k_zmean<<<(Bn * 128 + 255) / 256, 256, 0, stream>>>(zsum, zcnt, zmean, Bn);

  dec_col<<<256, Bn, 0, stream>>>(zmean, db1, d1_w, d1_b, bn1_g, bn1_b, 128, 256, Bn, 1);
  dec_col<<<128, Bn, 0, stream>>>(db1, db2, d2_w, d2_b, bn2_g, bn2_b, 256, 128, Bn, 1);
  dec_col<<<40, Bn, 0, stream>>>(db2, out, d3_w, d3_b, bn3_g, bn3_b, 128, 40, Bn, 0);
  k_argmax<<<1, 64, 0, stream>>>(out, out + Bn * 40, Bn, 40);
}

// Round 5
// 687.201 us; speedup vs baseline: 5.9120x; 1.1246x over previous
//
#include <hip/hip_runtime.h>
#include <math.h>

#define BN_EPS 1e-5f

typedef __attribute__((ext_vector_type(8))) short short8;
typedef __attribute__((ext_vector_type(4))) float f32x4;

__device__ __forceinline__ float bf2f(unsigned short u) {
  return __builtin_bit_cast(float, ((unsigned)u) << 16);
}
__device__ __forceinline__ unsigned short f2bf(float f) {
  unsigned u = __builtin_bit_cast(unsigned, f);
  unsigned r = (u + 0x7fffu + ((u >> 16) & 1u)) >> 16;
  return (unsigned short)r;
}
// split fp32 -> (hi, lo) bf16 pair; hi+lo reproduces x to ~2^-18 rel
__device__ __forceinline__ void fsplit(float x, unsigned short& h, unsigned short& l) {
  h = f2bf(x);
  l = f2bf(x - bf2f(h));
}

// ---------------------------------------------------------------------------
// Edge pass 1: int in-degree + scatter-sum of pos[src] into sum1[dst]
// ---------------------------------------------------------------------------
__global__ void k_deg_sum1(const int* __restrict__ src, const int* __restrict__ dst,
                           const float* __restrict__ pos, int* __restrict__ deg,
                           float* __restrict__ sum1, int E) {
  int e = blockIdx.x * blockDim.x + threadIdx.x;
  if (e >= E) return;
  int s = src[e], d = dst[e];
  atomicAdd(&deg[d], 1);
  atomicAdd(&sum1[d * 3 + 0], pos[s * 3 + 0]);
  atomicAdd(&sum1[d * 3 + 1], pos[s * 3 + 1]);
  atomicAdd(&sum1[d * 3 + 2], pos[s * 3 + 2]);
}

// ---------------------------------------------------------------------------
// Exclusive scan of deg -> rowptr
// ---------------------------------------------------------------------------
__global__ void k_scan1(const int* __restrict__ deg, int* __restrict__ rowptr,
                        int* __restrict__ bsum, int N) {
  __shared__ int part[256];
  int t = threadIdx.x;
  int base = blockIdx.x * 1024;
  int v[4]; int s = 0;
#pragma unroll
  for (int i = 0; i < 4; i++) {
    int idx = base + t * 4 + i;
    v[i] = (idx < N) ? deg[idx] : 0;
    s += v[i];
  }
  part[t] = s;
  __syncthreads();
  for (int off = 1; off < 256; off <<= 1) {
    int x = (t >= off) ? part[t - off] : 0;
    __syncthreads();
    part[t] += x;
    __syncthreads();
  }
  int run = part[t] - s;
#pragma unroll
  for (int i = 0; i < 4; i++) {
    int idx = base + t * 4 + i;
    if (idx < N) rowptr[idx] = run;
    run += v[i];
  }
  if (t == 255) bsum[blockIdx.x] = part[255];
}

__global__ void k_scan2(int* __restrict__ bsum, int nb) {
  if (threadIdx.x == 0 && blockIdx.x == 0) {
    int run = 0;
    for (int i = 0; i < nb; i++) { int v = bsum[i]; bsum[i] = run; run += v; }
  }
}

__global__ void k_scan3(int* __restrict__ rowptr, const int* __restrict__ bsum,
                        int N, int E) {
  int i = blockIdx.x * blockDim.x + threadIdx.x;
  if (i < N) rowptr[i] += bsum[i >> 10];
  else if (i == N) rowptr[N] = E;
}

__global__ void k_fill(const int* __restrict__ src, const int* __restrict__ dst,
                       const int* __restrict__ rowptr, int* __restrict__ fill,
                       int* __restrict__ col, int E) {
  int e = blockIdx.x * blockDim.x + threadIdx.x;
  if (e >= E) return;
  int d = dst[e];
  int p = rowptr[d] + atomicAdd(&fill[d], 1);
  col[p] = src[e];
}

// ---------------------------------------------------------------------------
// SAGE1: x1 = relu(wl @ (sum1/deg) + wr @ pos + b) -> catH/catL[:,0:128]
// ---------------------------------------------------------------------------
__global__ void k_sage1(const float* __restrict__ sum1, const int* __restrict__ deg,
                        const float* __restrict__ pos,
                        const float* __restrict__ wl, const float* __restrict__ wr,
                        const float* __restrict__ b,
                        unsigned short* __restrict__ catH, unsigned short* __restrict__ catL,
                        int N) {
  int n = blockIdx.x;
  if (n >= N) return;
  int o = threadIdx.x;  // 0..127
  float c = fmaxf((float)deg[n], 1.f);
  float a0 = sum1[n * 3 + 0] / c, a1 = sum1[n * 3 + 1] / c, a2 = sum1[n * 3 + 2] / c;
  float p0 = pos[n * 3 + 0], p1 = pos[n * 3 + 1], p2 = pos[n * 3 + 2];
  float v = b[o] + wl[o * 3 + 0] * a0 + wl[o * 3 + 1] * a1 + wl[o * 3 + 2] * a2
                 + wr[o * 3 + 0] * p0 + wr[o * 3 + 1] * p1 + wr[o * 3 + 2] * p2;
  v = fmaxf(v, 0.f);
  unsigned short h, l;
  fsplit(v, h, l);
  catH[(size_t)n * 256 + o] = h;
  catL[(size_t)n * 256 + o] = l;
}

// ---------------------------------------------------------------------------
// Mean-aggregate x1 over incoming edges (hi/lo), wave per node, 2x unroll.
// ---------------------------------------------------------------------------
__global__ void k_agg_x1(const int* __restrict__ rowptr, const int* __restrict__ col,
                         const unsigned short* __restrict__ catH,
                         const unsigned short* __restrict__ catL,
                         unsigned short* __restrict__ aggH,
                         unsigned short* __restrict__ aggL, int N) {
  int w = (blockIdx.x * blockDim.x + threadIdx.x) >> 6;
  int nw = (gridDim.x * blockDim.x) >> 6;
  int lane = threadIdx.x & 63;
  for (int n = w; n < N; n += nw) {
    int k0 = rowptr[n], k1 = rowptr[n + 1];
    float ax = 0.f, ay = 0.f;
    int k = k0;
    for (; k + 1 < k1; k += 2) {
      int s0 = col[k], s1 = col[k + 1];
      size_t b0 = (size_t)s0 * 256 + lane * 2;
      size_t b1 = (size_t)s1 * 256 + lane * 2;
      ushort2 h0 = *(const ushort2*)&catH[b0];
      ushort2 l0 = *(const ushort2*)&catL[b0];
      ushort2 h1 = *(const ushort2*)&catH[b1];
      ushort2 l1 = *(const ushort2*)&catL[b1];
      ax += (bf2f(h0.x) + bf2f(l0.x)) + (bf2f(h1.x) + bf2f(l1.x));
      ay += (bf2f(h0.y) + bf2f(l0.y)) + (bf2f(h1.y) + bf2f(l1.y));
    }
    if (k < k1) {
      int s = col[k];
      size_t b0 = (size_t)s * 256 + lane * 2;
      ushort2 vh = *(const ushort2*)&catH[b0];
      ushort2 vl = *(const ushort2*)&catL[b0];
      ax += bf2f(vh.x) + bf2f(vl.x);
      ay += bf2f(vh.y) + bf2f(vl.y);
    }
    float inv = 1.f / fmaxf((float)(k1 - k0), 1.f);
    unsigned short hx, lx, hy, ly;
    fsplit(ax * inv, hx, lx);
    fsplit(ay * inv, hy, ly);
    *(ushort2*)&aggH[(size_t)n * 128 + lane * 2] = make_ushort2(hx, hy);
    *(ushort2*)&aggL[(size_t)n * 128 + lane * 2] = make_ushort2(lx, ly);
  }
}

// ---------------------------------------------------------------------------
// Cast/concat fp32 weights -> bf16 hi/lo: k<K1 from a, else from b
// ---------------------------------------------------------------------------
__global__ void k_castcat(const float* __restrict__ a, const float* __restrict__ b,
                          unsigned short* __restrict__ oH, unsigned short* __restrict__ oL,
                          int K1, int K2, int M) {
  int i = blockIdx.x * blockDim.x + threadIdx.x;
  int K = K1 + K2;
  if (i >= M * K) return;
  int m = i / K, k = i - m * K;
  float v = (k < K1) ? a[m * K1 + k] : b[m * K2 + (k - K1)];
  unsigned short h, l;
  fsplit(v, h, l);
  oH[i] = h;
  oL[i] = l;
}

// ---------------------------------------------------------------------------
// Split-bf16 MFMA GEMM (fp32-equivalent): C = act(A . W^T + bias).
// A = Ah+Al, W = Wh+Wl; A.W ~= AhWh + AhWl + AlWh (3 MFMAs / frag pair).
// Tile 128x128, BK=64, 4 waves x (32 rows x 128 cols), mfma_f32_16x16x32_bf16.
// If attn != null (GAT projection): this block covers all K for head `bn`;
// epilogue computes per-row dots with asrc/adst (fp32 acc) and stores
// attn[rg*4 + bn] / attn[rg*4 + 2 + bn] directly — replaces k_attn kernel.
// ---------------------------------------------------------------------------
__global__ __launch_bounds__(256) void gemm_split(
    const unsigned short* __restrict__ AH1, const unsigned short* __restrict__ AL1,
    int as1, int K1,
    const unsigned short* __restrict__ AH2, const unsigned short* __restrict__ AL2,
    int as2,
    const unsigned short* __restrict__ WH, const unsigned short* __restrict__ WL,
    const float* __restrict__ bias,
    unsigned short* __restrict__ CH, unsigned short* __restrict__ CL,
    int cs, int co, int Nr, int K, int relu,
    const float* __restrict__ asrc, const float* __restrict__ adst,
    float* __restrict__ attn) {
  __shared__ unsigned short AsH[128][72];  // 144B row stride: odd multiple of 16B
  __shared__ unsigned short AsL[128][72];
  __shared__ unsigned short BsH[128][72];
  __shared__ unsigned short BsL[128][72];
  int tid = threadIdx.x;
  int bm = blockIdx.x, bn = blockIdx.y;
  int wv = tid >> 6, L = tid & 63;
  int m16 = L & 15, quad = L >> 4;
  int rbase = wv * 32;

  f32x4 acc[2][8];
#pragma unroll
  for (int i = 0; i < 2; i++)
#pragma unroll
    for (int j = 0; j < 8; j++) acc[i][j] = (f32x4){0.f, 0.f, 0.f, 0.f};

  for (int kt = 0; kt < K; kt += 64) {
    const unsigned short *ApH, *ApL;
    int ast, kl;
    if (kt < K1) { ApH = AH1; ApL = AL1; ast = as1; kl = kt; }
    else         { ApH = AH2; ApL = AL2; ast = as2; kl = kt - K1; }
#pragma unroll
    for (int i = 0; i < 4; i++) {
      int flat = tid * 4 + i;           // 0..1023
      int row = flat >> 3;              // 0..127
      int kc = (flat & 7) * 8;          // 0..56
      int rg = bm * 128 + row;
      uint4 vah = {0u, 0u, 0u, 0u}, val = {0u, 0u, 0u, 0u};
      if (rg < Nr) {
        size_t a = (size_t)rg * ast + kl + kc;
        vah = *(const uint4*)&ApH[a];
        val = *(const uint4*)&ApL[a];
      }
      *(uint4*)&AsH[row][kc] = vah;
      *(uint4*)&AsL[row][kc] = val;
      int ng = bn * 128 + row;
      size_t wb = (size_t)ng * K + kt + kc;
      *(uint4*)&BsH[row][kc] = *(const uint4*)&WH[wb];
      *(uint4*)&BsL[row][kc] = *(const uint4*)&WL[wb];
    }
    __syncthreads();
#pragma unroll
    for (int ks = 0; ks < 2; ks++) {
      short8 afH[2], afL[2];
#pragma unroll
      for (int rt = 0; rt < 2; rt++) {
        afH[rt] = *(const short8*)&AsH[rbase + rt * 16 + m16][ks * 32 + quad * 8];
        afL[rt] = *(const short8*)&AsL[rbase + rt * 16 + m16][ks * 32 + quad * 8];
      }
#pragma unroll
      for (int ct = 0; ct < 8; ct++) {
        short8 bfH = *(const short8*)&BsH[ct * 16 + m16][ks * 32 + quad * 8];
        short8 bfL = *(const short8*)&BsL[ct * 16 + m16][ks * 32 + quad * 8];
#pragma unroll
        for (int rt = 0; rt < 2; rt++) {
          acc[rt][ct] = __builtin_amdgcn_mfma_f32_16x16x32_bf16(afH[rt], bfH, acc[rt][ct], 0, 0, 0);
          acc[rt][ct] = __builtin_amdgcn_mfma_f32_16x16x32_bf16(afH[rt], bfL, acc[rt][ct], 0, 0, 0);
          acc[rt][ct] = __builtin_amdgcn_mfma_f32_16x16x32_bf16(afL[rt], bfH, acc[rt][ct], 0, 0, 0);
        }
      }
    }
    __syncthreads();
  }

  // epilogue: C/D layout col=lane&15, row=quad*4+reg
  const bool doattn = (attn != nullptr);
  float sa[2][4], sd[2][4];
#pragma unroll
  for (int rt = 0; rt < 2; rt++)
#pragma unroll
    for (int r = 0; r < 4; r++) { sa[rt][r] = 0.f; sd[rt][r] = 0.f; }

#pragma unroll
  for (int rt = 0; rt < 2; rt++) {
#pragma unroll
    for (int r = 0; r < 4; r++) {
      int rg = bm * 128 + rbase + rt * 16 + quad * 4 + r;
      if (rg >= Nr) continue;
#pragma unroll
      for (int ct = 0; ct < 8; ct++) {
        int cg = bn * 128 + ct * 16 + m16;
        float v = acc[rt][ct][r];
        if (doattn) {
          sa[rt][r] += v * asrc[cg];
          sd[rt][r] += v * adst[cg];
        }
        if (bias) v += bias[cg];
        if (relu) v = fmaxf(v, 0.f);
        unsigned short h, l;
        fsplit(v, h, l);
        size_t o = (size_t)rg * cs + co + cg;
        CH[o] = h;
        CL[o] = l;
      }
    }
  }

  if (doattn) {
#pragma unroll
    for (int rt = 0; rt < 2; rt++) {
#pragma unroll
      for (int r = 0; r < 4; r++) {
        float a = sa[rt][r], d = sd[rt][r];
#pragma unroll
        for (int m = 8; m >= 1; m >>= 1) {
          a += __shfl_xor(a, m);
          d += __shfl_xor(d, m);
        }
        if (m16 == 0) {
          int rg = bm * 128 + rbase + rt * 16 + quad * 4 + r;
          if (rg < Nr) {
            attn[rg * 4 + bn] = a;       // a_src, head bn
            attn[rg * 4 + 2 + bn] = d;   // a_dst, head bn
          }
        }
      }
    }
  }
}

// ---------------------------------------------------------------------------
// GAT: CSR gather over hi/lo xw, wave per node, 2x edge unroll.
// lanes 0..31 = head0 (ch 0..127), lanes 32..63 = head1 (ch 0..127).
// (softmax shift-invariance: skipping segment-max is mathematically identical)
// ---------------------------------------------------------------------------
__global__ void k_gat_gather(const int* __restrict__ rowptr, const int* __restrict__ col,
                             const unsigned short* __restrict__ xwH,
                             const unsigned short* __restrict__ xwL,
                             const float* __restrict__ attn,
                             const float* __restrict__ gb, float* __restrict__ x3g, int N) {
  int w = (blockIdx.x * blockDim.x + threadIdx.x) >> 6;
  int nw = (gridDim.x * blockDim.x) >> 6;
  int lane = threadIdx.x & 63;
  int h = lane >> 5;
  for (int n = w; n < N; n += nw) {
    int k0 = rowptr[n], k1 = rowptr[n + 1];
    float ad = attn[n * 4 + 2 + h];
    float a0 = 0.f, a1 = 0.f, a2 = 0.f, a3 = 0.f, den = 0.f;
    int k = k0;
    for (; k + 1 < k1; k += 2) {
      int s0 = col[k], s1 = col[k + 1];
      float e0 = attn[s0 * 4 + h] + ad;
      float e1 = attn[s1 * 4 + h] + ad;
      e0 = e0 >= 0.f ? e0 : 0.2f * e0;
      e1 = e1 >= 0.f ? e1 : 0.2f * e1;
      float w0 = expf(e0), w1 = expf(e1);
      size_t b0 = (size_t)s0 * 256 + lane * 4;
      size_t b1 = (size_t)s1 * 256 + lane * 4;
      ushort4 h0 = *(const ushort4*)&xwH[b0];
      ushort4 l0 = *(const ushort4*)&xwL[b0];
      ushort4 h1 = *(const ushort4*)&xwH[b1];
      ushort4 l1 = *(const ushort4*)&xwL[b1];
      a0 += w0 * (bf2f(h0.x) + bf2f(l0.x)) + w1 * (bf2f(h1.x) + bf2f(l1.x));
      a1 += w0 * (bf2f(h0.y) + bf2f(l0.y)) + w1 * (bf2f(h1.y) + bf2f(l1.y));
      a2 += w0 * (bf2f(h0.z) + bf2f(l0.z)) + w1 * (bf2f(h1.z) + bf2f(l1.z));
      a3 += w0 * (bf2f(h0.w) + bf2f(l0.w)) + w1 * (bf2f(h1.w) + bf2f(l1.w));
      den += w0 + w1;
    }
    if (k < k1) {
      int s = col[k];
      float ea = attn[s * 4 + h] + ad;
      float el = ea >= 0.f ? ea : 0.2f * ea;
      float wgt = expf(el);
      size_t base = (size_t)s * 256 + lane * 4;
      ushort4 xh = *(const ushort4*)&xwH[base];
      ushort4 xl = *(const ushort4*)&xwL[base];
      a0 += wgt * (bf2f(xh.x) + bf2f(xl.x));
      a1 += wgt * (bf2f(xh.y) + bf2f(xl.y));
      a2 += wgt * (bf2f(xh.z) + bf2f(xl.z));
      a3 += wgt * (bf2f(xh.w) + bf2f(xl.w));
      den += wgt;
    }
    {  // self-loop
      float ea = attn[n * 4 + h] + ad;
      float el = ea >= 0.f ? ea : 0.2f * ea;
      float wgt = expf(el);
      size_t base = (size_t)n * 256 + lane * 4;
      ushort4 xh = *(const ushort4*)&xwH[base];
      ushort4 xl = *(const ushort4*)&xwL[base];
      a0 += wgt * (bf2f(xh.x) + bf2f(xl.x));
      a1 += wgt * (bf2f(xh.y) + bf2f(xl.y));
      a2 += wgt * (bf2f(xh.z) + bf2f(xl.z));
      a3 += wgt * (bf2f(xh.w) + bf2f(xl.w));
      den += wgt;
    }
    float invD = 1.f / den;
    float q0 = a0 * invD, q1 = a1 * invD, q2 = a2 * invD, q3 = a3 * invD;
    float p0 = __shfl_xor(q0, 32), p1 = __shfl_xor(q1, 32);
    float p2 = __shfl_xor(q2, 32), p3 = __shfl_xor(q3, 32);
    if (lane < 32) {
      float invc = 1.f / (float)(k1 - k0 + 1);
      float4 g = *(const float4*)&gb[lane * 4];
      float4 r;
      r.x = 0.5f * (q0 + p0) * invc + g.x;
      r.y = 0.5f * (q1 + p1) * invc + g.y;
      r.z = 0.5f * (q2 + p2) * invc + g.z;
      r.w = 0.5f * (q3 + p3) * invc + g.w;
      *(float4*)&x3g[(size_t)n * 128 + lane * 4] = r;
    }
  }
}

// ---------------------------------------------------------------------------
// Global mean pool over sorted batch: run-length accumulate, flush on change
// ---------------------------------------------------------------------------
__global__ void k_pool(const float* __restrict__ x3g, const int* __restrict__ batch,
                       float* __restrict__ zsum, float* __restrict__ zcnt, int N) {
  int t = threadIdx.x;  // 0..127
  int chunk = (N + gridDim.x - 1) / gridDim.x;
  int n0 = blockIdx.x * chunk;
  int n1 = min(N, n0 + chunk);
  if (n0 >= n1) return;
  int cur = batch[n0];
  float acc = 0.f, cacc = 0.f;
  for (int n = n0; n < n1; n++) {
    int b = batch[n];
    if (b != cur) {
      atomicAdd(&zsum[cur * 128 + t], acc);
      if (t == 0) atomicAdd(&zcnt[cur], cacc);
      acc = 0.f; cacc = 0.f; cur = b;
    }
    acc += x3g[(size_t)n * 128 + t];
    cacc += 1.f;
  }
  atomicAdd(&zsum[cur * 128 + t], acc);
  if (t == 0) atomicAdd(&zcnt[cur], cacc);
}

__global__ void k_zmean(const float* __restrict__ zsum, const float* __restrict__ zcnt,
                        float* __restrict__ zmean, int Bn) {
  int i = blockIdx.x * blockDim.x + threadIdx.x;
  if (i >= Bn * 128) return;
  int b = i >> 7;
  zmean[i] = zsum[i] / fmaxf(zcnt[b], 1.f);
}

// ---------------------------------------------------------------------------
// Decoder layer, column-parallel: one block (1 wave, Bn=64 threads) per output
// column. Thread r = batch row. BN mean/var via wave shuffle. All fp32.
// ---------------------------------------------------------------------------
__global__ void dec_col(const float* __restrict__ X, float* __restrict__ Y,
                        const float* __restrict__ W, const float* __restrict__ bias,
                        const float* __restrict__ g, const float* __restrict__ beta,
                        int Ki, int Mo, int Bn, int relu) {
  int m = blockIdx.x;
  int r = threadIdx.x;  // 0..Bn-1 (Bn==64)
  float acc = bias[m];
  const float* xr = &X[(size_t)r * Ki];
  const float* wr = &W[(size_t)m * Ki];
  for (int k = 0; k < Ki; k += 4) {
    float4 xv = *(const float4*)&xr[k];
    float4 wv = *(const float4*)&wr[k];
    acc += xv.x * wv.x + xv.y * wv.y + xv.z * wv.z + xv.w * wv.w;
  }
  float s = acc;
#pragma unroll
  for (int o = 32; o >= 1; o >>= 1) s += __shfl_xor(s, o);
  float mean = s / (float)Bn;
  float d = acc - mean;
  float v2 = d * d;
#pragma unroll
  for (int o = 32; o >= 1; o >>= 1) v2 += __shfl_xor(v2, o);
  float var = v2 / (float)Bn;
  float y = g[m] * d / sqrtf(var + BN_EPS) + beta[m];
  if (relu) y = fmaxf(y, 0.f);
  Y[(size_t)r * Mo + m] = y;
}

__global__ void k_argmax(const float* __restrict__ z, float* __restrict__ argout,
                         int Bn, int Mo) {
  int r = blockIdx.x * blockDim.x + threadIdx.x;
  if (r >= Bn) return;
  const float* yr = &z[(size_t)r * Mo];
  float best = yr[0];
  int bi = 0;
  for (int j = 1; j < Mo; j++)
    if (yr[j] > best) { best = yr[j]; bi = j; }
  argout[r] = (float)bi;
}

// ---------------------------------------------------------------------------
extern "C" void kernel_launch(void* const* d_in, const int* in_sizes, int n_in,
                              void* d_out, int out_size, void* d_ws, size_t ws_size,
                              hipStream_t stream) {
  const int N = in_sizes[0] / 3;
  const int E = in_sizes[1] / 2;
  const int Bn = out_size / 41;  // z [B,40] + argmax [B]

  const float* pos = (const float*)d_in[0];
  const int* ei = (const int*)d_in[1];
  const int* src = ei;
  const int* dst = ei + E;
  const int* batch = (const int*)d_in[2];
  const float* s1_wl = (const float*)d_in[3];
  const float* s1_wr = (const float*)d_in[4];
  const float* s1_b  = (const float*)d_in[5];
  const float* s2_wl = (const float*)d_in[6];
  const float* s2_wr = (const float*)d_in[7];
  const float* s2_b  = (const float*)d_in[8];
  const float* g_w    = (const float*)d_in[9];
  const float* g_asrc = (const float*)d_in[10];
  const float* g_adst = (const float*)d_in[11];
  const float* g_b    = (const float*)d_in[12];
  const float* d1_w = (const float*)d_in[13];
  const float* d1_b = (const float*)d_in[14];
  const float* bn1_g = (const float*)d_in[15];
  const float* bn1_b = (const float*)d_in[16];
  const float* d2_w = (const float*)d_in[17];
  const float* d2_b = (const float*)d_in[18];
  const float* bn2_g = (const float*)d_in[19];
  const float* bn2_b = (const float*)d_in[20];
  const float* d3_w = (const float*)d_in[21];
  const float* d3_b = (const float*)d_in[22];
  const float* bn3_g = (const float*)d_in[23];
  const float* bn3_b = (const float*)d_in[24];

  size_t Ns = (size_t)N, Es = (size_t)E;
  char* p = (char*)d_ws;
  auto take = [&](size_t bytes) -> char* {
    char* r = p;
    p += (bytes + 255) & ~(size_t)255;
    return r;
  };
  int* deg    = (int*)take(Ns * 4);
  int* fillc  = (int*)take(Ns * 4);
  int* rowptr = (int*)take((Ns + 1) * 4);
  int* bsums  = (int*)take(1024);
  int* col    = (int*)take(Es * 4);
  float* sum1 = (float*)take(3 * Ns * 4);
  float* attn = (float*)take(4 * Ns * 4);
  unsigned short* catH = (unsigned short*)take(256 * Ns * 2);  // [x1|x2] hi
  unsigned short* catL = (unsigned short*)take(256 * Ns * 2);  // [x1|x2] lo
  unsigned short* aggH = (unsigned short*)take(128 * Ns * 2);  // mean-agg hi
  unsigned short* aggL = (unsigned short*)take(128 * Ns * 2);  // mean-agg lo
  unsigned short* xwH  = (unsigned short*)take(256 * Ns * 2);  // GAT proj hi
  unsigned short* xwL  = (unsigned short*)take(256 * Ns * 2);  // GAT proj lo
  unsigned short* wcH  = (unsigned short*)take(128 * 256 * 2); // [s2_wl|s2_wr] hi
  unsigned short* wcL  = (unsigned short*)take(128 * 256 * 2);
  unsigned short* gwH  = (unsigned short*)take(256 * 256 * 2); // g_w hi
  unsigned short* gwL  = (unsigned short*)take(256 * 256 * 2);
  float* zsum  = (float*)take(8192 * 4);
  float* zcnt  = (float*)take(256 * 4);
  float* zmean = (float*)take(8192 * 4);
  float* db1   = (float*)take(16384 * 4);
  float* db2   = (float*)take(8192 * 4);
  // x3g reuses the agg hi/lo region (agg dead after GEMM1): 128N fp32 = 2*128N bf16
  float* x3g = (float*)aggH;
  float* out = (float*)d_out;

  hipMemsetAsync(deg, 0, Ns * 4, stream);
  hipMemsetAsync(fillc, 0, Ns * 4, stream);
  hipMemsetAsync(sum1, 0, 3 * Ns * 4, stream);
  hipMemsetAsync(zsum, 0, 8192 * 4, stream);
  hipMemsetAsync(zcnt, 0, 256 * 4, stream);

  k_deg_sum1<<<(E + 255) / 256, 256, 0, stream>>>(src, dst, pos, deg, sum1, E);

  int nb = (N + 1023) / 1024;
  k_scan1<<<nb, 256, 0, stream>>>(deg, rowptr, bsums, N);
  k_scan2<<<1, 64, 0, stream>>>(bsums, nb);
  k_scan3<<<(N + 256) / 256, 256, 0, stream>>>(rowptr, bsums, N, E);
  k_fill<<<(E + 255) / 256, 256, 0, stream>>>(src, dst, rowptr, fillc, col, E);

  // weight casts (independent)
  k_castcat<<<(128 * 256 + 255) / 256, 256, 0, stream>>>(s2_wl, s2_wr, wcH, wcL, 128, 128, 128);
  k_castcat<<<(256 * 256 + 255) / 256, 256, 0, stream>>>(g_w, nullptr, gwH, gwL, 256, 0, 256);

  k_sage1<<<N, 128, 0, stream>>>(sum1, deg, pos, s1_wl, s1_wr, s1_b, catH, catL, N);
  k_agg_x1<<<2048, 256, 0, stream>>>(rowptr, col, catH, catL, aggH, aggL, N);

  // SAGE2: x2 = relu([agg|x1] @ [wl|wr].T + b) -> cat[:,128:256]
  dim3 g2((N + 127) / 128, 1);
  gemm_split<<<g2, 256, 0, stream>>>(aggH, aggL, 128, 128, catH, catL, 256,
                                     wcH, wcL, s2_b, catH, catL, 256, 128, N, 256, 1,
                                     nullptr, nullptr, nullptr);

  // GAT projection: xw = [x1|x2] @ g_w.T -> xwH/xwL, with fused attention dots
  dim3 g3((N + 127) / 128, 2);
  gemm_split<<<g3, 256, 0, stream>>>(catH, catL, 256, 256, nullptr, nullptr, 0,
                                     gwH, gwL, nullptr, xwH, xwL, 256, 0, N, 256, 0,
                                     g_asrc, g_adst, attn);

  k_gat_gather<<<2048, 256, 0, stream>>>(rowptr, col, xwH, xwL, attn, g_b, x3g, N);

  k_pool<<<2048, 128, 0, stream>>>(x3g, batch, zsum, zcnt, N);
  k_zmean<<<(Bn * 128 + 255) / 256, 256, 0, stream>>>(zsum, zcnt, zmean, Bn);

  dec_col<<<256, Bn, 0, stream>>>(zmean, db1, d1_w, d1_b, bn1_g, bn1_b, 128, 256, Bn, 1);
  dec_col<<<128, Bn, 0, stream>>>(db1, db2, d2_w, d2_b, bn2_g, bn2_b, 256, 128, Bn, 1);
  dec_col<<<40, Bn, 0, stream>>>(db2, out, d3_w, d3_b, bn3_g, bn3_b, 128, 40, Bn, 0);
  k_argmax<<<1, 64, 0, stream>>>(out, out + Bn * 40, Bn, 40);
}

// Round 6
// 684.418 us; speedup vs baseline: 5.9361x; 1.0041x over previous
//
#include <hip/hip_runtime.h>
#include <math.h>

#define BN_EPS 1e-5f

typedef __attribute__((ext_vector_type(8))) short short8;
typedef __attribute__((ext_vector_type(4))) float f32x4;

__device__ __forceinline__ float bf2f(unsigned short u) {
  return __builtin_bit_cast(float, ((unsigned)u) << 16);
}
__device__ __forceinline__ unsigned short f2bf(float f) {
  unsigned u = __builtin_bit_cast(unsigned, f);
  unsigned r = (u + 0x7fffu + ((u >> 16) & 1u)) >> 16;
  return (unsigned short)r;
}
// split fp32 -> (hi, lo) bf16 pair; hi+lo reproduces x to ~2^-18 rel
__device__ __forceinline__ void fsplit(float x, unsigned short& h, unsigned short& l) {
  h = f2bf(x);
  l = f2bf(x - bf2f(h));
}

// ---------------------------------------------------------------------------
// Edge pass 1: int in-degree + scatter-sum of pos[src] into sum1[dst]
// ---------------------------------------------------------------------------
__global__ void k_deg_sum1(const int* __restrict__ src, const int* __restrict__ dst,
                           const float* __restrict__ pos, int* __restrict__ deg,
                           float* __restrict__ sum1, int E) {
  int e = blockIdx.x * blockDim.x + threadIdx.x;
  if (e >= E) return;
  int s = src[e], d = dst[e];
  atomicAdd(&deg[d], 1);
  atomicAdd(&sum1[d * 3 + 0], pos[s * 3 + 0]);
  atomicAdd(&sum1[d * 3 + 1], pos[s * 3 + 1]);
  atomicAdd(&sum1[d * 3 + 2], pos[s * 3 + 2]);
}

// ---------------------------------------------------------------------------
// Exclusive scan of deg -> rowptr
// ---------------------------------------------------------------------------
__global__ void k_scan1(const int* __restrict__ deg, int* __restrict__ rowptr,
                        int* __restrict__ bsum, int N) {
  __shared__ int part[256];
  int t = threadIdx.x;
  int base = blockIdx.x * 1024;
  int v[4]; int s = 0;
#pragma unroll
  for (int i = 0; i < 4; i++) {
    int idx = base + t * 4 + i;
    v[i] = (idx < N) ? deg[idx] : 0;
    s += v[i];
  }
  part[t] = s;
  __syncthreads();
  for (int off = 1; off < 256; off <<= 1) {
    int x = (t >= off) ? part[t - off] : 0;
    __syncthreads();
    part[t] += x;
    __syncthreads();
  }
  int run = part[t] - s;
#pragma unroll
  for (int i = 0; i < 4; i++) {
    int idx = base + t * 4 + i;
    if (idx < N) rowptr[idx] = run;
    run += v[i];
  }
  if (t == 255) bsum[blockIdx.x] = part[255];
}

__global__ void k_scan2(int* __restrict__ bsum, int nb) {
  if (threadIdx.x == 0 && blockIdx.x == 0) {
    int run = 0;
    for (int i = 0; i < nb; i++) { int v = bsum[i]; bsum[i] = run; run += v; }
  }
}

__global__ void k_scan3(int* __restrict__ rowptr, const int* __restrict__ bsum,
                        int N, int E) {
  int i = blockIdx.x * blockDim.x + threadIdx.x;
  if (i < N) rowptr[i] += bsum[i >> 10];
  else if (i == N) rowptr[N] = E;
}

__global__ void k_fill(const int* __restrict__ src, const int* __restrict__ dst,
                       const int* __restrict__ rowptr, int* __restrict__ fill,
                       int* __restrict__ col, int E) {
  int e = blockIdx.x * blockDim.x + threadIdx.x;
  if (e >= E) return;
  int d = dst[e];
  int p = rowptr[d] + atomicAdd(&fill[d], 1);
  col[p] = src[e];
}

// ---------------------------------------------------------------------------
// SAGE1: x1 = relu(wl @ (sum1/deg) + wr @ pos + b) -> catH/catL[:,0:128]
// ---------------------------------------------------------------------------
__global__ void k_sage1(const float* __restrict__ sum1, const int* __restrict__ deg,
                        const float* __restrict__ pos,
                        const float* __restrict__ wl, const float* __restrict__ wr,
                        const float* __restrict__ b,
                        unsigned short* __restrict__ catH, unsigned short* __restrict__ catL,
                        int N) {
  int n = blockIdx.x;
  if (n >= N) return;
  int o = threadIdx.x;  // 0..127
  float c = fmaxf((float)deg[n], 1.f);
  float a0 = sum1[n * 3 + 0] / c, a1 = sum1[n * 3 + 1] / c, a2 = sum1[n * 3 + 2] / c;
  float p0 = pos[n * 3 + 0], p1 = pos[n * 3 + 1], p2 = pos[n * 3 + 2];
  float v = b[o] + wl[o * 3 + 0] * a0 + wl[o * 3 + 1] * a1 + wl[o * 3 + 2] * a2
                 + wr[o * 3 + 0] * p0 + wr[o * 3 + 1] * p1 + wr[o * 3 + 2] * p2;
  v = fmaxf(v, 0.f);
  unsigned short h, l;
  fsplit(v, h, l);
  catH[(size_t)n * 256 + o] = h;
  catL[(size_t)n * 256 + o] = l;
}

// ---------------------------------------------------------------------------
// Mean-aggregate x1 over incoming edges (hi/lo), wave per node, 2x unroll.
// ---------------------------------------------------------------------------
__global__ void k_agg_x1(const int* __restrict__ rowptr, const int* __restrict__ col,
                         const unsigned short* __restrict__ catH,
                         const unsigned short* __restrict__ catL,
                         unsigned short* __restrict__ aggH,
                         unsigned short* __restrict__ aggL, int N) {
  int w = (blockIdx.x * blockDim.x + threadIdx.x) >> 6;
  int nw = (gridDim.x * blockDim.x) >> 6;
  int lane = threadIdx.x & 63;
  for (int n = w; n < N; n += nw) {
    int k0 = rowptr[n], k1 = rowptr[n + 1];
    float ax = 0.f, ay = 0.f;
    int k = k0;
    for (; k + 1 < k1; k += 2) {
      int s0 = col[k], s1 = col[k + 1];
      size_t b0 = (size_t)s0 * 256 + lane * 2;
      size_t b1 = (size_t)s1 * 256 + lane * 2;
      ushort2 h0 = *(const ushort2*)&catH[b0];
      ushort2 l0 = *(const ushort2*)&catL[b0];
      ushort2 h1 = *(const ushort2*)&catH[b1];
      ushort2 l1 = *(const ushort2*)&catL[b1];
      ax += (bf2f(h0.x) + bf2f(l0.x)) + (bf2f(h1.x) + bf2f(l1.x));
      ay += (bf2f(h0.y) + bf2f(l0.y)) + (bf2f(h1.y) + bf2f(l1.y));
    }
    if (k < k1) {
      int s = col[k];
      size_t b0 = (size_t)s * 256 + lane * 2;
      ushort2 vh = *(const ushort2*)&catH[b0];
      ushort2 vl = *(const ushort2*)&catL[b0];
      ax += bf2f(vh.x) + bf2f(vl.x);
      ay += bf2f(vh.y) + bf2f(vl.y);
    }
    float inv = 1.f / fmaxf((float)(k1 - k0), 1.f);
    unsigned short hx, lx, hy, ly;
    fsplit(ax * inv, hx, lx);
    fsplit(ay * inv, hy, ly);
    *(ushort2*)&aggH[(size_t)n * 128 + lane * 2] = make_ushort2(hx, hy);
    *(ushort2*)&aggL[(size_t)n * 128 + lane * 2] = make_ushort2(lx, ly);
  }
}

// ---------------------------------------------------------------------------
// Cast/concat fp32 weights -> bf16 hi/lo: k<K1 from a, else from b
// ---------------------------------------------------------------------------
__global__ void k_castcat(const float* __restrict__ a, const float* __restrict__ b,
                          unsigned short* __restrict__ oH, unsigned short* __restrict__ oL,
                          int K1, int K2, int M) {
  int i = blockIdx.x * blockDim.x + threadIdx.x;
  int K = K1 + K2;
  if (i >= M * K) return;
  int m = i / K, k = i - m * K;
  float v = (k < K1) ? a[m * K1 + k] : b[m * K2 + (k - K1)];
  unsigned short h, l;
  fsplit(v, h, l);
  oH[i] = h;
  oL[i] = l;
}

// ---------------------------------------------------------------------------
// Split-bf16 MFMA GEMM (fp32-equivalent): C = act(A . W^T + bias).
// A = Ah+Al, W = Wh+Wl; A.W ~= AhWh + AhWl + AlWh (3 MFMAs / frag pair).
// Tile 128x128, BK=32 (LDS 40 KB -> 4 blocks/CU for latency hiding),
// 4 waves x (32 rows x 128 cols), mfma_f32_16x16x32_bf16.
// If attn != null (GAT projection): epilogue computes per-row dots with
// asrc/adst (fp32 acc) and stores attn directly — replaces k_attn kernel.
// ---------------------------------------------------------------------------
__global__ __launch_bounds__(256) void gemm_split(
    const unsigned short* __restrict__ AH1, const unsigned short* __restrict__ AL1,
    int as1, int K1,
    const unsigned short* __restrict__ AH2, const unsigned short* __restrict__ AL2,
    int as2,
    const unsigned short* __restrict__ WH, const unsigned short* __restrict__ WL,
    const float* __restrict__ bias,
    unsigned short* __restrict__ CH, unsigned short* __restrict__ CL,
    int cs, int co, int Nr, int K, int relu,
    const float* __restrict__ asrc, const float* __restrict__ adst,
    float* __restrict__ attn) {
  // 80 B row stride (20 banks, odd multiple of 16 B): 2-way conflicts on
  // b128 frag reads (free), 4-way on staging writes (cheap).
  __shared__ unsigned short AsH[128][40];
  __shared__ unsigned short AsL[128][40];
  __shared__ unsigned short BsH[128][40];
  __shared__ unsigned short BsL[128][40];
  int tid = threadIdx.x;
  int bm = blockIdx.x, bn = blockIdx.y;
  int wv = tid >> 6, L = tid & 63;
  int m16 = L & 15, quad = L >> 4;
  int rbase = wv * 32;

  f32x4 acc[2][8];
#pragma unroll
  for (int i = 0; i < 2; i++)
#pragma unroll
    for (int j = 0; j < 8; j++) acc[i][j] = (f32x4){0.f, 0.f, 0.f, 0.f};

  for (int kt = 0; kt < K; kt += 32) {
    const unsigned short *ApH, *ApL;
    int ast, kl;
    if (kt < K1) { ApH = AH1; ApL = AL1; ast = as1; kl = kt; }
    else         { ApH = AH2; ApL = AL2; ast = as2; kl = kt - K1; }
#pragma unroll
    for (int i = 0; i < 2; i++) {
      int flat = tid * 2 + i;           // 0..511
      int row = flat >> 2;              // 0..127
      int kc = (flat & 3) * 8;          // 0,8,16,24
      int rg = bm * 128 + row;
      uint4 vah = {0u, 0u, 0u, 0u}, val = {0u, 0u, 0u, 0u};
      if (rg < Nr) {
        size_t a = (size_t)rg * ast + kl + kc;
        vah = *(const uint4*)&ApH[a];
        val = *(const uint4*)&ApL[a];
      }
      *(uint4*)&AsH[row][kc] = vah;
      *(uint4*)&AsL[row][kc] = val;
      int ng = bn * 128 + row;
      size_t wb = (size_t)ng * K + kt + kc;
      *(uint4*)&BsH[row][kc] = *(const uint4*)&WH[wb];
      *(uint4*)&BsL[row][kc] = *(const uint4*)&WL[wb];
    }
    __syncthreads();
    short8 afH[2], afL[2];
#pragma unroll
    for (int rt = 0; rt < 2; rt++) {
      afH[rt] = *(const short8*)&AsH[rbase + rt * 16 + m16][quad * 8];
      afL[rt] = *(const short8*)&AsL[rbase + rt * 16 + m16][quad * 8];
    }
#pragma unroll
    for (int ct = 0; ct < 8; ct++) {
      short8 bfH = *(const short8*)&BsH[ct * 16 + m16][quad * 8];
      short8 bfL = *(const short8*)&BsL[ct * 16 + m16][quad * 8];
#pragma unroll
      for (int rt = 0; rt < 2; rt++) {
        acc[rt][ct] = __builtin_amdgcn_mfma_f32_16x16x32_bf16(afH[rt], bfH, acc[rt][ct], 0, 0, 0);
        acc[rt][ct] = __builtin_amdgcn_mfma_f32_16x16x32_bf16(afH[rt], bfL, acc[rt][ct], 0, 0, 0);
        acc[rt][ct] = __builtin_amdgcn_mfma_f32_16x16x32_bf16(afL[rt], bfH, acc[rt][ct], 0, 0, 0);
      }
    }
    __syncthreads();
  }

  // epilogue: C/D layout col=lane&15, row=quad*4+reg
  const bool doattn = (attn != nullptr);
  float sa[2][4], sd[2][4];
#pragma unroll
  for (int rt = 0; rt < 2; rt++)
#pragma unroll
    for (int r = 0; r < 4; r++) { sa[rt][r] = 0.f; sd[rt][r] = 0.f; }

#pragma unroll
  for (int rt = 0; rt < 2; rt++) {
#pragma unroll
    for (int r = 0; r < 4; r++) {
      int rg = bm * 128 + rbase + rt * 16 + quad * 4 + r;
      if (rg >= Nr) continue;
#pragma unroll
      for (int ct = 0; ct < 8; ct++) {
        int cg = bn * 128 + ct * 16 + m16;
        float v = acc[rt][ct][r];
        if (doattn) {
          sa[rt][r] += v * asrc[cg];
          sd[rt][r] += v * adst[cg];
        }
        if (bias) v += bias[cg];
        if (relu) v = fmaxf(v, 0.f);
        unsigned short h, l;
        fsplit(v, h, l);
        size_t o = (size_t)rg * cs + co + cg;
        CH[o] = h;
        CL[o] = l;
      }
    }
  }

  if (doattn) {
#pragma unroll
    for (int rt = 0; rt < 2; rt++) {
#pragma unroll
      for (int r = 0; r < 4; r++) {
        float a = sa[rt][r], d = sd[rt][r];
#pragma unroll
        for (int m = 8; m >= 1; m >>= 1) {
          a += __shfl_xor(a, m);
          d += __shfl_xor(d, m);
        }
        if (m16 == 0) {
          int rg = bm * 128 + rbase + rt * 16 + quad * 4 + r;
          if (rg < Nr) {
            attn[rg * 4 + bn] = a;       // a_src, head bn
            attn[rg * 4 + 2 + bn] = d;   // a_dst, head bn
          }
        }
      }
    }
  }
}

// ---------------------------------------------------------------------------
// GAT: CSR gather over hi/lo xw, wave per node, 2x edge unroll.
// lanes 0..31 = head0 (ch 0..127), lanes 32..63 = head1 (ch 0..127).
// (softmax shift-invariance: skipping segment-max is mathematically identical)
// ---------------------------------------------------------------------------
__global__ void k_gat_gather(const int* __restrict__ rowptr, const int* __restrict__ col,
                             const unsigned short* __restrict__ xwH,
                             const unsigned short* __restrict__ xwL,
                             const float* __restrict__ attn,
                             const float* __restrict__ gb, float* __restrict__ x3g, int N) {
  int w = (blockIdx.x * blockDim.x + threadIdx.x) >> 6;
  int nw = (gridDim.x * blockDim.x) >> 6;
  int lane = threadIdx.x & 63;
  int h = lane >> 5;
  for (int n = w; n < N; n += nw) {
    int k0 = rowptr[n], k1 = rowptr[n + 1];
    float ad = attn[n * 4 + 2 + h];
    float a0 = 0.f, a1 = 0.f, a2 = 0.f, a3 = 0.f, den = 0.f;
    int k = k0;
    for (; k + 1 < k1; k += 2) {
      int s0 = col[k], s1 = col[k + 1];
      float e0 = attn[s0 * 4 + h] + ad;
      float e1 = attn[s1 * 4 + h] + ad;
      e0 = e0 >= 0.f ? e0 : 0.2f * e0;
      e1 = e1 >= 0.f ? e1 : 0.2f * e1;
      float w0 = expf(e0), w1 = expf(e1);
      size_t b0 = (size_t)s0 * 256 + lane * 4;
      size_t b1 = (size_t)s1 * 256 + lane * 4;
      ushort4 h0 = *(const ushort4*)&xwH[b0];
      ushort4 l0 = *(const ushort4*)&xwL[b0];
      ushort4 h1 = *(const ushort4*)&xwH[b1];
      ushort4 l1 = *(const ushort4*)&xwL[b1];
      a0 += w0 * (bf2f(h0.x) + bf2f(l0.x)) + w1 * (bf2f(h1.x) + bf2f(l1.x));
      a1 += w0 * (bf2f(h0.y) + bf2f(l0.y)) + w1 * (bf2f(h1.y) + bf2f(l1.y));
      a2 += w0 * (bf2f(h0.z) + bf2f(l0.z)) + w1 * (bf2f(h1.z) + bf2f(l1.z));
      a3 += w0 * (bf2f(h0.w) + bf2f(l0.w)) + w1 * (bf2f(h1.w) + bf2f(l1.w));
      den += w0 + w1;
    }
    if (k < k1) {
      int s = col[k];
      float ea = attn[s * 4 + h] + ad;
      float el = ea >= 0.f ? ea : 0.2f * ea;
      float wgt = expf(el);
      size_t base = (size_t)s * 256 + lane * 4;
      ushort4 xh = *(const ushort4*)&xwH[base];
      ushort4 xl = *(const ushort4*)&xwL[base];
      a0 += wgt * (bf2f(xh.x) + bf2f(xl.x));
      a1 += wgt * (bf2f(xh.y) + bf2f(xl.y));
      a2 += wgt * (bf2f(xh.z) + bf2f(xl.z));
      a3 += wgt * (bf2f(xh.w) + bf2f(xl.w));
      den += wgt;
    }
    {  // self-loop
      float ea = attn[n * 4 + h] + ad;
      float el = ea >= 0.f ? ea : 0.2f * ea;
      float wgt = expf(el);
      size_t base = (size_t)n * 256 + lane * 4;
      ushort4 xh = *(const ushort4*)&xwH[base];
      ushort4 xl = *(const ushort4*)&xwL[base];
      a0 += wgt * (bf2f(xh.x) + bf2f(xl.x));
      a1 += wgt * (bf2f(xh.y) + bf2f(xl.y));
      a2 += wgt * (bf2f(xh.z) + bf2f(xl.z));
      a3 += wgt * (bf2f(xh.w) + bf2f(xl.w));
      den += wgt;
    }
    float invD = 1.f / den;
    float q0 = a0 * invD, q1 = a1 * invD, q2 = a2 * invD, q3 = a3 * invD;
    float p0 = __shfl_xor(q0, 32), p1 = __shfl_xor(q1, 32);
    float p2 = __shfl_xor(q2, 32), p3 = __shfl_xor(q3, 32);
    if (lane < 32) {
      float invc = 1.f / (float)(k1 - k0 + 1);
      float4 g = *(const float4*)&gb[lane * 4];
      float4 r;
      r.x = 0.5f * (q0 + p0) * invc + g.x;
      r.y = 0.5f * (q1 + p1) * invc + g.y;
      r.z = 0.5f * (q2 + p2) * invc + g.z;
      r.w = 0.5f * (q3 + p3) * invc + g.w;
      *(float4*)&x3g[(size_t)n * 128 + lane * 4] = r;
    }
  }
}

// ---------------------------------------------------------------------------
// Global mean pool over sorted batch: run-length accumulate, flush on change
// ---------------------------------------------------------------------------
__global__ void k_pool(const float* __restrict__ x3g, const int* __restrict__ batch,
                       float* __restrict__ zsum, float* __restrict__ zcnt, int N) {
  int t = threadIdx.x;  // 0..127
  int chunk = (N + gridDim.x - 1) / gridDim.x;
  int n0 = blockIdx.x * chunk;
  int n1 = min(N, n0 + chunk);
  if (n0 >= n1) return;
  int cur = batch[n0];
  float acc = 0.f, cacc = 0.f;
  for (int n = n0; n < n1; n++) {
    int b = batch[n];
    if (b != cur) {
      atomicAdd(&zsum[cur * 128 + t], acc);
      if (t == 0) atomicAdd(&zcnt[cur], cacc);
      acc = 0.f; cacc = 0.f; cur = b;
    }
    acc += x3g[(size_t)n * 128 + t];
    cacc += 1.f;
  }
  atomicAdd(&zsum[cur * 128 + t], acc);
  if (t == 0) atomicAdd(&zcnt[cur], cacc);
}

// ---------------------------------------------------------------------------
// Decoder layer, column-parallel: one block (1 wave, Bn=64 threads) per output
// column. Thread r = batch row. BN mean/var via wave shuffle. All fp32.
// If zcntp != null, input rows are zsum and get scaled by 1/max(zcnt,1)
// (fused global-mean-pool normalize — linear, algebraically identical).
// ---------------------------------------------------------------------------
__global__ void dec_col(const float* __restrict__ X, float* __restrict__ Y,
                        const float* __restrict__ W, const float* __restrict__ bias,
                        const float* __restrict__ g, const float* __restrict__ beta,
                        int Ki, int Mo, int Bn, int relu,
                        const float* __restrict__ zcntp) {
  int m = blockIdx.x;
  int r = threadIdx.x;  // 0..Bn-1 (Bn==64)
  float dot = 0.f;
  const float* xr = &X[(size_t)r * Ki];
  const float* wr = &W[(size_t)m * Ki];
  for (int k = 0; k < Ki; k += 4) {
    float4 xv = *(const float4*)&xr[k];
    float4 wv = *(const float4*)&wr[k];
    dot += xv.x * wv.x + xv.y * wv.y + xv.z * wv.z + xv.w * wv.w;
  }
  if (zcntp) dot *= 1.f / fmaxf(zcntp[r], 1.f);
  float acc = dot + bias[m];
  float s = acc;
#pragma unroll
  for (int o = 32; o >= 1; o >>= 1) s += __shfl_xor(s, o);
  float mean = s / (float)Bn;
  float d = acc - mean;
  float v2 = d * d;
#pragma unroll
  for (int o = 32; o >= 1; o >>= 1) v2 += __shfl_xor(v2, o);
  float var = v2 / (float)Bn;
  float y = g[m] * d / sqrtf(var + BN_EPS) + beta[m];
  if (relu) y = fmaxf(y, 0.f);
  Y[(size_t)r * Mo + m] = y;
}

__global__ void k_argmax(const float* __restrict__ z, float* __restrict__ argout,
                         int Bn, int Mo) {
  int r = blockIdx.x * blockDim.x + threadIdx.x;
  if (r >= Bn) return;
  const float* yr = &z[(size_t)r * Mo];
  float best = yr[0];
  int bi = 0;
  for (int j = 1; j < Mo; j++)
    if (yr[j] > best) { best = yr[j]; bi = j; }
  argout[r] = (float)bi;
}

// ---------------------------------------------------------------------------
extern "C" void kernel_launch(void* const* d_in, const int* in_sizes, int n_in,
                              void* d_out, int out_size, void* d_ws, size_t ws_size,
                              hipStream_t stream) {
  const int N = in_sizes[0] / 3;
  const int E = in_sizes[1] / 2;
  const int Bn = out_size / 41;  // z [B,40] + argmax [B]

  const float* pos = (const float*)d_in[0];
  const int* ei = (const int*)d_in[1];
  const int* src = ei;
  const int* dst = ei + E;
  const int* batch = (const int*)d_in[2];
  const float* s1_wl = (const float*)d_in[3];
  const float* s1_wr = (const float*)d_in[4];
  const float* s1_b  = (const float*)d_in[5];
  const float* s2_wl = (const float*)d_in[6];
  const float* s2_wr = (const float*)d_in[7];
  const float* s2_b  = (const float*)d_in[8];
  const float* g_w    = (const float*)d_in[9];
  const float* g_asrc = (const float*)d_in[10];
  const float* g_adst = (const float*)d_in[11];
  const float* g_b    = (const float*)d_in[12];
  const float* d1_w = (const float*)d_in[13];
  const float* d1_b = (const float*)d_in[14];
  const float* bn1_g = (const float*)d_in[15];
  const float* bn1_b = (const float*)d_in[16];
  const float* d2_w = (const float*)d_in[17];
  const float* d2_b = (const float*)d_in[18];
  const float* bn2_g = (const float*)d_in[19];
  const float* bn2_b = (const float*)d_in[20];
  const float* d3_w = (const float*)d_in[21];
  const float* d3_b = (const float*)d_in[22];
  const float* bn3_g = (const float*)d_in[23];
  const float* bn3_b = (const float*)d_in[24];

  size_t Ns = (size_t)N, Es = (size_t)E;
  char* p = (char*)d_ws;
  auto take = [&](size_t bytes) -> char* {
    char* r = p;
    p += (bytes + 255) & ~(size_t)255;
    return r;
  };
  int* deg    = (int*)take(Ns * 4);
  int* fillc  = (int*)take(Ns * 4);
  int* rowptr = (int*)take((Ns + 1) * 4);
  int* bsums  = (int*)take(1024);
  int* col    = (int*)take(Es * 4);
  float* sum1 = (float*)take(3 * Ns * 4);
  float* attn = (float*)take(4 * Ns * 4);
  unsigned short* catH = (unsigned short*)take(256 * Ns * 2);  // [x1|x2] hi
  unsigned short* catL = (unsigned short*)take(256 * Ns * 2);  // [x1|x2] lo
  unsigned short* aggH = (unsigned short*)take(128 * Ns * 2);  // mean-agg hi
  unsigned short* aggL = (unsigned short*)take(128 * Ns * 2);  // mean-agg lo
  unsigned short* xwH  = (unsigned short*)take(256 * Ns * 2);  // GAT proj hi
  unsigned short* xwL  = (unsigned short*)take(256 * Ns * 2);  // GAT proj lo
  unsigned short* wcH  = (unsigned short*)take(128 * 256 * 2); // [s2_wl|s2_wr] hi
  unsigned short* wcL  = (unsigned short*)take(128 * 256 * 2);
  unsigned short* gwH  = (unsigned short*)take(256 * 256 * 2); // g_w hi
  unsigned short* gwL  = (unsigned short*)take(256 * 256 * 2);
  float* zsum  = (float*)take(8192 * 4);
  float* zcnt  = (float*)take(256 * 4);
  float* db1   = (float*)take(16384 * 4);
  float* db2   = (float*)take(8192 * 4);
  // x3g reuses the agg hi/lo region (agg dead after GEMM1): 128N fp32 = 2*128N bf16
  float* x3g = (float*)aggH;
  float* out = (float*)d_out;

  hipMemsetAsync(deg, 0, Ns * 4, stream);
  hipMemsetAsync(fillc, 0, Ns * 4, stream);
  hipMemsetAsync(sum1, 0, 3 * Ns * 4, stream);
  hipMemsetAsync(zsum, 0, 8192 * 4, stream);
  hipMemsetAsync(zcnt, 0, 256 * 4, stream);

  k_deg_sum1<<<(E + 255) / 256, 256, 0, stream>>>(src, dst, pos, deg, sum1, E);

  int nb = (N + 1023) / 1024;
  k_scan1<<<nb, 256, 0, stream>>>(deg, rowptr, bsums, N);
  k_scan2<<<1, 64, 0, stream>>>(bsums, nb);
  k_scan3<<<(N + 256) / 256, 256, 0, stream>>>(rowptr, bsums, N, E);
  k_fill<<<(E + 255) / 256, 256, 0, stream>>>(src, dst, rowptr, fillc, col, E);

  // weight casts (independent)
  k_castcat<<<(128 * 256 + 255) / 256, 256, 0, stream>>>(s2_wl, s2_wr, wcH, wcL, 128, 128, 128);
  k_castcat<<<(256 * 256 + 255) / 256, 256, 0, stream>>>(g_w, nullptr, gwH, gwL, 256, 0, 256);

  k_sage1<<<N, 128, 0, stream>>>(sum1, deg, pos, s1_wl, s1_wr, s1_b, catH, catL, N);
  k_agg_x1<<<2048, 256, 0, stream>>>(rowptr, col, catH, catL, aggH, aggL, N);

  // SAGE2: x2 = relu([agg|x1] @ [wl|wr].T + b) -> cat[:,128:256]
  dim3 g2((N + 127) / 128, 1);
  gemm_split<<<g2, 256, 0, stream>>>(aggH, aggL, 128, 128, catH, catL, 256,
                                     wcH, wcL, s2_b, catH, catL, 256, 128, N, 256, 1,
                                     nullptr, nullptr, nullptr);

  // GAT projection: xw = [x1|x2] @ g_w.T -> xwH/xwL, with fused attention dots
  dim3 g3((N + 127) / 128, 2);
  gemm_split<<<g3, 256, 0, stream>>>(catH, catL, 256, 256, nullptr, nullptr, 0,
                                     gwH, gwL, nullptr, xwH, xwL, 256, 0, N, 256, 0,
                                     g_asrc, g_adst, attn);

  k_gat_gather<<<2048, 256, 0, stream>>>(rowptr, col, xwH, xwL, attn, g_b, x3g, N);

  k_pool<<<2048, 128, 0, stream>>>(x3g, batch, zsum, zcnt, N);

  // decoder (zmean fused into first layer via zcnt row-scale)
  dec_col<<<256, Bn, 0, stream>>>(zsum, db1, d1_w, d1_b, bn1_g, bn1_b, 128, 256, Bn, 1, zcnt);
  dec_col<<<128, Bn, 0, stream>>>(db1, db2, d2_w, d2_b, bn2_g, bn2_b, 256, 128, Bn, 1, nullptr);
  dec_col<<<40, Bn, 0, stream>>>(db2, out, d3_w, d3_b, bn3_g, bn3_b, 128, 40, Bn, 0, nullptr);
  k_argmax<<<1, 64, 0, stream>>>(out, out + Bn * 40, Bn, 40);
}

// Round 7
// 639.809 us; speedup vs baseline: 6.3499x; 1.0697x over previous
//
#include <hip/hip_runtime.h>
#include <math.h>

#define BN_EPS 1e-5f

typedef __attribute__((ext_vector_type(8))) short short8;
typedef __attribute__((ext_vector_type(4))) float f32x4;
typedef unsigned int uint_t;

__device__ __forceinline__ float bf2f(unsigned short u) {
  return __builtin_bit_cast(float, ((unsigned)u) << 16);
}
__device__ __forceinline__ unsigned short f2bf(float f) {
  unsigned u = __builtin_bit_cast(unsigned, f);
  unsigned r = (u + 0x7fffu + ((u >> 16) & 1u)) >> 16;
  return (unsigned short)r;
}
// split fp32 -> packed (hi | lo<<16) bf16 pair; hi+lo reproduces x to ~2^-18 rel
__device__ __forceinline__ uint_t packsplit(float x) {
  unsigned short h = f2bf(x);
  unsigned short l = f2bf(x - bf2f(h));
  return (uint_t)h | ((uint_t)l << 16);
}
__device__ __forceinline__ float unpk(uint_t u) {
  return bf2f((unsigned short)(u & 0xffffu)) + bf2f((unsigned short)(u >> 16));
}

// ---------------------------------------------------------------------------
// Edge pass 1: int in-degree + scatter-sum of pos[src] into sum1[dst]
// ---------------------------------------------------------------------------
__global__ void k_deg_sum1(const int* __restrict__ src, const int* __restrict__ dst,
                           const float* __restrict__ pos, int* __restrict__ deg,
                           float* __restrict__ sum1, int E) {
  int e = blockIdx.x * blockDim.x + threadIdx.x;
  if (e >= E) return;
  int s = src[e], d = dst[e];
  atomicAdd(&deg[d], 1);
  atomicAdd(&sum1[d * 3 + 0], pos[s * 3 + 0]);
  atomicAdd(&sum1[d * 3 + 1], pos[s * 3 + 1]);
  atomicAdd(&sum1[d * 3 + 2], pos[s * 3 + 2]);
}

// ---------------------------------------------------------------------------
// Exclusive scan of deg -> rowptr
// ---------------------------------------------------------------------------
__global__ void k_scan1(const int* __restrict__ deg, int* __restrict__ rowptr,
                        int* __restrict__ bsum, int N) {
  __shared__ int part[256];
  int t = threadIdx.x;
  int base = blockIdx.x * 1024;
  int v[4]; int s = 0;
#pragma unroll
  for (int i = 0; i < 4; i++) {
    int idx = base + t * 4 + i;
    v[i] = (idx < N) ? deg[idx] : 0;
    s += v[i];
  }
  part[t] = s;
  __syncthreads();
  for (int off = 1; off < 256; off <<= 1) {
    int x = (t >= off) ? part[t - off] : 0;
    __syncthreads();
    part[t] += x;
    __syncthreads();
  }
  int run = part[t] - s;
#pragma unroll
  for (int i = 0; i < 4; i++) {
    int idx = base + t * 4 + i;
    if (idx < N) rowptr[idx] = run;
    run += v[i];
  }
  if (t == 255) bsum[blockIdx.x] = part[255];
}

__global__ void k_scan2(int* __restrict__ bsum, int nb) {
  if (threadIdx.x == 0 && blockIdx.x == 0) {
    int run = 0;
    for (int i = 0; i < nb; i++) { int v = bsum[i]; bsum[i] = run; run += v; }
  }
}

__global__ void k_scan3(int* __restrict__ rowptr, const int* __restrict__ bsum,
                        int N, int E) {
  int i = blockIdx.x * blockDim.x + threadIdx.x;
  if (i < N) rowptr[i] += bsum[i >> 10];
  else if (i == N) rowptr[N] = E;
}

__global__ void k_fill(const int* __restrict__ src, const int* __restrict__ dst,
                       const int* __restrict__ rowptr, int* __restrict__ fill,
                       int* __restrict__ col, int E) {
  int e = blockIdx.x * blockDim.x + threadIdx.x;
  if (e >= E) return;
  int d = dst[e];
  int p = rowptr[d] + atomicAdd(&fill[d], 1);
  col[p] = src[e];
}

// ---------------------------------------------------------------------------
// SAGE1: x1 = relu(wl @ (sum1/deg) + wr @ pos + b) -> cat[:,0:128] packed
// ---------------------------------------------------------------------------
__global__ void k_sage1(const float* __restrict__ sum1, const int* __restrict__ deg,
                        const float* __restrict__ pos,
                        const float* __restrict__ wl, const float* __restrict__ wr,
                        const float* __restrict__ b,
                        uint_t* __restrict__ cat, int N) {
  int n = blockIdx.x;
  if (n >= N) return;
  int o = threadIdx.x;  // 0..127
  float c = fmaxf((float)deg[n], 1.f);
  float a0 = sum1[n * 3 + 0] / c, a1 = sum1[n * 3 + 1] / c, a2 = sum1[n * 3 + 2] / c;
  float p0 = pos[n * 3 + 0], p1 = pos[n * 3 + 1], p2 = pos[n * 3 + 2];
  float v = b[o] + wl[o * 3 + 0] * a0 + wl[o * 3 + 1] * a1 + wl[o * 3 + 2] * a2
                 + wr[o * 3 + 0] * p0 + wr[o * 3 + 1] * p1 + wr[o * 3 + 2] * p2;
  cat[(size_t)n * 256 + o] = packsplit(fmaxf(v, 0.f));
}

// ---------------------------------------------------------------------------
// Mean-aggregate x1 over incoming edges (packed hi/lo), wave per node, 2x unroll.
// ---------------------------------------------------------------------------
__global__ void k_agg_x1(const int* __restrict__ rowptr, const int* __restrict__ col,
                         const uint_t* __restrict__ cat,
                         uint_t* __restrict__ agg, int N) {
  int w = (blockIdx.x * blockDim.x + threadIdx.x) >> 6;
  int nw = (gridDim.x * blockDim.x) >> 6;
  int lane = threadIdx.x & 63;
  for (int n = w; n < N; n += nw) {
    int k0 = rowptr[n], k1 = rowptr[n + 1];
    float ax = 0.f, ay = 0.f;
    int k = k0;
    for (; k + 1 < k1; k += 2) {
      int s0 = col[k], s1 = col[k + 1];
      uint2 v0 = *(const uint2*)&cat[(size_t)s0 * 256 + lane * 2];
      uint2 v1 = *(const uint2*)&cat[(size_t)s1 * 256 + lane * 2];
      ax += unpk(v0.x) + unpk(v1.x);
      ay += unpk(v0.y) + unpk(v1.y);
    }
    if (k < k1) {
      int s = col[k];
      uint2 v = *(const uint2*)&cat[(size_t)s * 256 + lane * 2];
      ax += unpk(v.x);
      ay += unpk(v.y);
    }
    float inv = 1.f / fmaxf((float)(k1 - k0), 1.f);
    uint2 o;
    o.x = packsplit(ax * inv);
    o.y = packsplit(ay * inv);
    *(uint2*)&agg[(size_t)n * 128 + lane * 2] = o;
  }
}

// ---------------------------------------------------------------------------
// Cast/concat fp32 weights -> bf16 hi/lo (separate arrays, GEMM B-operand)
// ---------------------------------------------------------------------------
__global__ void k_castcat(const float* __restrict__ a, const float* __restrict__ b,
                          unsigned short* __restrict__ oH, unsigned short* __restrict__ oL,
                          int K1, int K2, int M) {
  int i = blockIdx.x * blockDim.x + threadIdx.x;
  int K = K1 + K2;
  if (i >= M * K) return;
  int m = i / K, k = i - m * K;
  float v = (k < K1) ? a[m * K1 + k] : b[m * K2 + (k - K1)];
  unsigned short h = f2bf(v);
  oH[i] = h;
  oL[i] = f2bf(v - bf2f(h));
}

// ---------------------------------------------------------------------------
// Split-bf16 MFMA GEMM (fp32-equivalent): C = act(A . W^T + bias).
// A packed (hi|lo per uint), W as separate hi/lo bf16 arrays.
// A.W ~= AhWh + AhWl + AlWh (3 MFMAs / frag pair). Tile 128x128, BK=32,
// 4 waves x (32 rows x 128 cols), mfma_f32_16x16x32_bf16.
// Epilogue: (opt) fused attention dots; then C-tile routed through an LDS
// transpose so global writes are coalesced dwordx4 (16 wide stores/thread
// instead of 128 scalar 2B stores — the R6 bottleneck).
// ---------------------------------------------------------------------------
__global__ __launch_bounds__(256) void gemm_split(
    const uint_t* __restrict__ A1, int as1, int K1,
    const uint_t* __restrict__ A2, int as2,
    const unsigned short* __restrict__ WH, const unsigned short* __restrict__ WL,
    const float* __restrict__ bias,
    uint_t* __restrict__ C, int cs, int co, int Nr, int K, int relu,
    const float* __restrict__ asrc, const float* __restrict__ adst,
    float* __restrict__ attn) {
  // one flat LDS pool: 4 staging tiles [128][40] ushort = 40960 B;
  // reused as transpose buffer [128][65] uint = 33280 B.
  __shared__ unsigned short smem[4 * 128 * 40];
  unsigned short (*AsH)[40] = (unsigned short (*)[40])smem;
  unsigned short (*AsL)[40] = (unsigned short (*)[40])(smem + 128 * 40);
  unsigned short (*BsH)[40] = (unsigned short (*)[40])(smem + 2 * 128 * 40);
  unsigned short (*BsL)[40] = (unsigned short (*)[40])(smem + 3 * 128 * 40);
  int tid = threadIdx.x;
  int bm = blockIdx.x, bn = blockIdx.y;
  int wv = tid >> 6, L = tid & 63;
  int m16 = L & 15, quad = L >> 4;
  int rbase = wv * 32;

  f32x4 acc[2][8];
#pragma unroll
  for (int i = 0; i < 2; i++)
#pragma unroll
    for (int j = 0; j < 8; j++) acc[i][j] = (f32x4){0.f, 0.f, 0.f, 0.f};

  for (int kt = 0; kt < K; kt += 32) {
    const uint_t* Ap;
    int ast, kl;
    if (kt < K1) { Ap = A1; ast = as1; kl = kt; }
    else         { Ap = A2; ast = as2; kl = kt - K1; }
#pragma unroll
    for (int i = 0; i < 2; i++) {
      int flat = tid * 2 + i;           // 0..511
      int row = flat >> 2;              // 0..127
      int kc = (flat & 3) * 8;          // 0,8,16,24
      int rg = bm * 128 + row;
      uint4 p0 = {0u, 0u, 0u, 0u}, p1 = {0u, 0u, 0u, 0u};
      if (rg < Nr) {
        const uint_t* ap = &Ap[(size_t)rg * ast + kl + kc];
        p0 = *(const uint4*)ap;
        p1 = *(const uint4*)(ap + 4);
      }
      // deinterleave packed (hi|lo) words into hi-pair / lo-pair words
      uint_t h0 = (p0.x & 0xffffu) | (p0.y << 16), l0 = (p0.x >> 16) | (p0.y & 0xffff0000u);
      uint_t h1 = (p0.z & 0xffffu) | (p0.w << 16), l1 = (p0.z >> 16) | (p0.w & 0xffff0000u);
      uint_t h2 = (p1.x & 0xffffu) | (p1.y << 16), l2 = (p1.x >> 16) | (p1.y & 0xffff0000u);
      uint_t h3 = (p1.z & 0xffffu) | (p1.w << 16), l3 = (p1.z >> 16) | (p1.w & 0xffff0000u);
      *(uint4*)&AsH[row][kc] = make_uint4(h0, h1, h2, h3);
      *(uint4*)&AsL[row][kc] = make_uint4(l0, l1, l2, l3);
      int ng = bn * 128 + row;
      size_t wb = (size_t)ng * K + kt + kc;
      *(uint4*)&BsH[row][kc] = *(const uint4*)&WH[wb];
      *(uint4*)&BsL[row][kc] = *(const uint4*)&WL[wb];
    }
    __syncthreads();
    short8 afH[2], afL[2];
#pragma unroll
    for (int rt = 0; rt < 2; rt++) {
      afH[rt] = *(const short8*)&AsH[rbase + rt * 16 + m16][quad * 8];
      afL[rt] = *(const short8*)&AsL[rbase + rt * 16 + m16][quad * 8];
    }
#pragma unroll
    for (int ct = 0; ct < 8; ct++) {
      short8 bfH = *(const short8*)&BsH[ct * 16 + m16][quad * 8];
      short8 bfL = *(const short8*)&BsL[ct * 16 + m16][quad * 8];
#pragma unroll
      for (int rt = 0; rt < 2; rt++) {
        acc[rt][ct] = __builtin_amdgcn_mfma_f32_16x16x32_bf16(afH[rt], bfH, acc[rt][ct], 0, 0, 0);
        acc[rt][ct] = __builtin_amdgcn_mfma_f32_16x16x32_bf16(afH[rt], bfL, acc[rt][ct], 0, 0, 0);
        acc[rt][ct] = __builtin_amdgcn_mfma_f32_16x16x32_bf16(afL[rt], bfH, acc[rt][ct], 0, 0, 0);
      }
    }
    __syncthreads();
  }

  // ---- fused attention dots (GAT projection only), from raw acc ----
  if (attn) {
#pragma unroll
    for (int rt = 0; rt < 2; rt++) {
#pragma unroll
      for (int r = 0; r < 4; r++) {
        float a = 0.f, d = 0.f;
#pragma unroll
        for (int ct = 0; ct < 8; ct++) {
          int cg = bn * 128 + ct * 16 + m16;
          float v = acc[rt][ct][r];
          a += v * asrc[cg];
          d += v * adst[cg];
        }
#pragma unroll
        for (int m = 8; m >= 1; m >>= 1) {
          a += __shfl_xor(a, m);
          d += __shfl_xor(d, m);
        }
        if (m16 == 0) {
          int rg = bm * 128 + rbase + rt * 16 + quad * 4 + r;
          if (rg < Nr) {
            attn[rg * 4 + bn] = a;       // a_src, head bn
            attn[rg * 4 + 2 + bn] = d;   // a_dst, head bn
          }
        }
      }
    }
  }

  // ---- epilogue: bias/relu/pack, LDS transpose, coalesced dwordx4 stores ----
  uint_t* T = (uint_t*)smem;  // [128][65]
#pragma unroll
  for (int hc = 0; hc < 2; hc++) {   // column halves of 64
    if (hc) __syncthreads();
    // write phase: lanes deposit packed values at [row][localcol]
#pragma unroll
    for (int rt = 0; rt < 2; rt++) {
#pragma unroll
      for (int ctl = 0; ctl < 4; ctl++) {
        int ct = hc * 4 + ctl;
        int cg = bn * 128 + ct * 16 + m16;
        float bco = bias ? bias[cg] : 0.f;
#pragma unroll
        for (int r = 0; r < 4; r++) {
          int row = rbase + rt * 16 + quad * 4 + r;
          float v = acc[rt][ct][r] + bco;
          if (relu) v = fmaxf(v, 0.f);
          T[row * 65 + ctl * 16 + m16] = packsplit(v);
        }
      }
    }
    __syncthreads();
    // read + wide store: thread t -> row t>>1, 32-col subchunk (t&1)
    int row = tid >> 1;
    int cb = (tid & 1) * 32;
    int rg = bm * 128 + row;
    if (rg < Nr) {
      size_t base = (size_t)rg * cs + co + bn * 128 + hc * 64 + cb;
#pragma unroll
      for (int i2 = 0; i2 < 8; i2++) {
        uint4 q = *(const uint4*)&T[row * 65 + cb + i2 * 4];
        *(uint4*)&C[base + i2 * 4] = q;
      }
    }
  }
}

// ---------------------------------------------------------------------------
// GAT: CSR gather over packed xw, wave per node, 2x edge unroll.
// lanes 0..31 = head0 (ch 0..127), lanes 32..63 = head1 (ch 0..127).
// (softmax shift-invariance: skipping segment-max is mathematically identical)
// ---------------------------------------------------------------------------
__global__ void k_gat_gather(const int* __restrict__ rowptr, const int* __restrict__ col,
                             const uint_t* __restrict__ xw,
                             const float* __restrict__ attn,
                             const float* __restrict__ gb, float* __restrict__ x3g, int N) {
  int w = (blockIdx.x * blockDim.x + threadIdx.x) >> 6;
  int nw = (gridDim.x * blockDim.x) >> 6;
  int lane = threadIdx.x & 63;
  int h = lane >> 5;
  for (int n = w; n < N; n += nw) {
    int k0 = rowptr[n], k1 = rowptr[n + 1];
    float ad = attn[n * 4 + 2 + h];
    float a0 = 0.f, a1 = 0.f, a2 = 0.f, a3 = 0.f, den = 0.f;
    int k = k0;
    for (; k + 1 < k1; k += 2) {
      int s0 = col[k], s1 = col[k + 1];
      float e0 = attn[s0 * 4 + h] + ad;
      float e1 = attn[s1 * 4 + h] + ad;
      e0 = e0 >= 0.f ? e0 : 0.2f * e0;
      e1 = e1 >= 0.f ? e1 : 0.2f * e1;
      float w0 = expf(e0), w1 = expf(e1);
      uint4 x0 = *(const uint4*)&xw[(size_t)s0 * 256 + lane * 4];
      uint4 x1 = *(const uint4*)&xw[(size_t)s1 * 256 + lane * 4];
      a0 += w0 * unpk(x0.x) + w1 * unpk(x1.x);
      a1 += w0 * unpk(x0.y) + w1 * unpk(x1.y);
      a2 += w0 * unpk(x0.z) + w1 * unpk(x1.z);
      a3 += w0 * unpk(x0.w) + w1 * unpk(x1.w);
      den += w0 + w1;
    }
    if (k < k1) {
      int s = col[k];
      float ea = attn[s * 4 + h] + ad;
      float el = ea >= 0.f ? ea : 0.2f * ea;
      float wgt = expf(el);
      uint4 x = *(const uint4*)&xw[(size_t)s * 256 + lane * 4];
      a0 += wgt * unpk(x.x); a1 += wgt * unpk(x.y);
      a2 += wgt * unpk(x.z); a3 += wgt * unpk(x.w);
      den += wgt;
    }
    {  // self-loop
      float ea = attn[n * 4 + h] + ad;
      float el = ea >= 0.f ? ea : 0.2f * ea;
      float wgt = expf(el);
      uint4 x = *(const uint4*)&xw[(size_t)n * 256 + lane * 4];
      a0 += wgt * unpk(x.x); a1 += wgt * unpk(x.y);
      a2 += wgt * unpk(x.z); a3 += wgt * unpk(x.w);
      den += wgt;
    }
    float invD = 1.f / den;
    float q0 = a0 * invD, q1 = a1 * invD, q2 = a2 * invD, q3 = a3 * invD;
    float p0 = __shfl_xor(q0, 32), p1 = __shfl_xor(q1, 32);
    float p2 = __shfl_xor(q2, 32), p3 = __shfl_xor(q3, 32);
    if (lane < 32) {
      float invc = 1.f / (float)(k1 - k0 + 1);
      float4 g = *(const float4*)&gb[lane * 4];
      float4 r;
      r.x = 0.5f * (q0 + p0) * invc + g.x;
      r.y = 0.5f * (q1 + p1) * invc + g.y;
      r.z = 0.5f * (q2 + p2) * invc + g.z;
      r.w = 0.5f * (q3 + p3) * invc + g.w;
      *(float4*)&x3g[(size_t)n * 128 + lane * 4] = r;
    }
  }
}

// ---------------------------------------------------------------------------
// Global mean pool over sorted batch: run-length accumulate, flush on change
// ---------------------------------------------------------------------------
__global__ void k_pool(const float* __restrict__ x3g, const int* __restrict__ batch,
                       float* __restrict__ zsum, float* __restrict__ zcnt, int N) {
  int t = threadIdx.x;  // 0..127
  int chunk = (N + gridDim.x - 1) / gridDim.x;
  int n0 = blockIdx.x * chunk;
  int n1 = min(N, n0 + chunk);
  if (n0 >= n1) return;
  int cur = batch[n0];
  float acc = 0.f, cacc = 0.f;
  for (int n = n0; n < n1; n++) {
    int b = batch[n];
    if (b != cur) {
      atomicAdd(&zsum[cur * 128 + t], acc);
      if (t == 0) atomicAdd(&zcnt[cur], cacc);
      acc = 0.f; cacc = 0.f; cur = b;
    }
    acc += x3g[(size_t)n * 128 + t];
    cacc += 1.f;
  }
  atomicAdd(&zsum[cur * 128 + t], acc);
  if (t == 0) atomicAdd(&zcnt[cur], cacc);
}

// ---------------------------------------------------------------------------
// Decoder layer, column-parallel: one block (1 wave, Bn=64 threads) per output
// column. Thread r = batch row. BN mean/var via wave shuffle. All fp32.
// If zcntp != null, input rows are zsum and get scaled by 1/max(zcnt,1)
// (fused global-mean-pool normalize — linear, algebraically identical).
// ---------------------------------------------------------------------------
__global__ void dec_col(const float* __restrict__ X, float* __restrict__ Y,
                        const float* __restrict__ W, const float* __restrict__ bias,
                        const float* __restrict__ g, const float* __restrict__ beta,
                        int Ki, int Mo, int Bn, int relu,
                        const float* __restrict__ zcntp) {
  int m = blockIdx.x;
  int r = threadIdx.x;  // 0..Bn-1 (Bn==64)
  float dot = 0.f;
  const float* xr = &X[(size_t)r * Ki];
  const float* wr = &W[(size_t)m * Ki];
  for (int k = 0; k < Ki; k += 4) {
    float4 xv = *(const float4*)&xr[k];
    float4 wv = *(const float4*)&wr[k];
    dot += xv.x * wv.x + xv.y * wv.y + xv.z * wv.z + xv.w * wv.w;
  }
  if (zcntp) dot *= 1.f / fmaxf(zcntp[r], 1.f);
  float acc = dot + bias[m];
  float s = acc;
#pragma unroll
  for (int o = 32; o >= 1; o >>= 1) s += __shfl_xor(s, o);
  float mean = s / (float)Bn;
  float d = acc - mean;
  float v2 = d * d;
#pragma unroll
  for (int o = 32; o >= 1; o >>= 1) v2 += __shfl_xor(v2, o);
  float var = v2 / (float)Bn;
  float y = g[m] * d / sqrtf(var + BN_EPS) + beta[m];
  if (relu) y = fmaxf(y, 0.f);
  Y[(size_t)r * Mo + m] = y;
}

__global__ void k_argmax(const float* __restrict__ z, float* __restrict__ argout,
                         int Bn, int Mo) {
  int r = blockIdx.x * blockDim.x + threadIdx.x;
  if (r >= Bn) return;
  const float* yr = &z[(size_t)r * Mo];
  float best = yr[0];
  int bi = 0;
  for (int j = 1; j < Mo; j++)
    if (yr[j] > best) { best = yr[j]; bi = j; }
  argout[r] = (float)bi;
}

// ---------------------------------------------------------------------------
extern "C" void kernel_launch(void* const* d_in, const int* in_sizes, int n_in,
                              void* d_out, int out_size, void* d_ws, size_t ws_size,
                              hipStream_t stream) {
  const int N = in_sizes[0] / 3;
  const int E = in_sizes[1] / 2;
  const int Bn = out_size / 41;  // z [B,40] + argmax [B]

  const float* pos = (const float*)d_in[0];
  const int* ei = (const int*)d_in[1];
  const int* src = ei;
  const int* dst = ei + E;
  const int* batch = (const int*)d_in[2];
  const float* s1_wl = (const float*)d_in[3];
  const float* s1_wr = (const float*)d_in[4];
  const float* s1_b  = (const float*)d_in[5];
  const float* s2_wl = (const float*)d_in[6];
  const float* s2_wr = (const float*)d_in[7];
  const float* s2_b  = (const float*)d_in[8];
  const float* g_w    = (const float*)d_in[9];
  const float* g_asrc = (const float*)d_in[10];
  const float* g_adst = (const float*)d_in[11];
  const float* g_b    = (const float*)d_in[12];
  const float* d1_w = (const float*)d_in[13];
  const float* d1_b = (const float*)d_in[14];
  const float* bn1_g = (const float*)d_in[15];
  const float* bn1_b = (const float*)d_in[16];
  const float* d2_w = (const float*)d_in[17];
  const float* d2_b = (const float*)d_in[18];
  const float* bn2_g = (const float*)d_in[19];
  const float* bn2_b = (const float*)d_in[20];
  const float* d3_w = (const float*)d_in[21];
  const float* d3_b = (const float*)d_in[22];
  const float* bn3_g = (const float*)d_in[23];
  const float* bn3_b = (const float*)d_in[24];

  size_t Ns = (size_t)N, Es = (size_t)E;
  char* p = (char*)d_ws;
  auto take = [&](size_t bytes) -> char* {
    char* r = p;
    p += (bytes + 255) & ~(size_t)255;
    return r;
  };
  int* deg    = (int*)take(Ns * 4);
  int* fillc  = (int*)take(Ns * 4);
  int* rowptr = (int*)take((Ns + 1) * 4);
  int* bsums  = (int*)take(1024);
  int* col    = (int*)take(Es * 4);
  float* sum1 = (float*)take(3 * Ns * 4);
  float* attn = (float*)take(4 * Ns * 4);
  uint_t* cat = (uint_t*)take(256 * Ns * 4);  // [x1|x2] packed hi|lo
  uint_t* agg = (uint_t*)take(128 * Ns * 4);  // mean-agg packed
  uint_t* xw  = (uint_t*)take(256 * Ns * 4);  // GAT proj packed
  unsigned short* wcH = (unsigned short*)take(128 * 256 * 2); // [s2_wl|s2_wr] hi
  unsigned short* wcL = (unsigned short*)take(128 * 256 * 2);
  unsigned short* gwH = (unsigned short*)take(256 * 256 * 2); // g_w hi
  unsigned short* gwL = (unsigned short*)take(256 * 256 * 2);
  float* zsum  = (float*)take(8192 * 4);
  float* zcnt  = (float*)take(256 * 4);
  float* db1   = (float*)take(16384 * 4);
  float* db2   = (float*)take(8192 * 4);
  // x3g reuses the agg region (agg dead after GEMM1): both 128N x 4B
  float* x3g = (float*)agg;
  float* out = (float*)d_out;

  hipMemsetAsync(deg, 0, Ns * 4, stream);
  hipMemsetAsync(fillc, 0, Ns * 4, stream);
  hipMemsetAsync(sum1, 0, 3 * Ns * 4, stream);
  hipMemsetAsync(zsum, 0, 8192 * 4, stream);
  hipMemsetAsync(zcnt, 0, 256 * 4, stream);

  k_deg_sum1<<<(E + 255) / 256, 256, 0, stream>>>(src, dst, pos, deg, sum1, E);

  int nb = (N + 1023) / 1024;
  k_scan1<<<nb, 256, 0, stream>>>(deg, rowptr, bsums, N);
  k_scan2<<<1, 64, 0, stream>>>(bsums, nb);
  k_scan3<<<(N + 256) / 256, 256, 0, stream>>>(rowptr, bsums, N, E);
  k_fill<<<(E + 255) / 256, 256, 0, stream>>>(src, dst, rowptr, fillc, col, E);

  // weight casts (independent)
  k_castcat<<<(128 * 256 + 255) / 256, 256, 0, stream>>>(s2_wl, s2_wr, wcH, wcL, 128, 128, 128);
  k_castcat<<<(256 * 256 + 255) / 256, 256, 0, stream>>>(g_w, nullptr, gwH, gwL, 256, 0, 256);

  k_sage1<<<N, 128, 0, stream>>>(sum1, deg, pos, s1_wl, s1_wr, s1_b, cat, N);
  k_agg_x1<<<2048, 256, 0, stream>>>(rowptr, col, cat, agg, N);

  // SAGE2: x2 = relu([agg|x1] @ [wl|wr].T + b) -> cat[:,128:256]
  dim3 g2((N + 127) / 128, 1);
  gemm_split<<<g2, 256, 0, stream>>>(agg, 128, 128, cat, 256,
                                     wcH, wcL, s2_b, cat, 256, 128, N, 256, 1,
                                     nullptr, nullptr, nullptr);

  // GAT projection: xw = [x1|x2] @ g_w.T -> xw, with fused attention dots
  dim3 g3((N + 127) / 128, 2);
  gemm_split<<<g3, 256, 0, stream>>>(cat, 256, 256, nullptr, 0,
                                     gwH, gwL, nullptr, xw, 256, 0, N, 256, 0,
                                     g_asrc, g_adst, attn);

  k_gat_gather<<<2048, 256, 0, stream>>>(rowptr, col, xw, attn, g_b, x3g, N);

  k_pool<<<2048, 128, 0, stream>>>(x3g, batch, zsum, zcnt, N);

  // decoder (zmean fused into first layer via zcnt row-scale)
  dec_col<<<256, Bn, 0, stream>>>(zsum, db1, d1_w, d1_b, bn1_g, bn1_b, 128, 256, Bn, 1, zcnt);
  dec_col<<<128, Bn, 0, stream>>>(db1, db2, d2_w, d2_b, bn2_g, bn2_b, 256, 128, Bn, 1, nullptr);
  dec_col<<<40, Bn, 0, stream>>>(db2, out, d3_w, d3_b, bn3_g, bn3_b, 128, 40, Bn, 0, nullptr);
  k_argmax<<<1, 64, 0, stream>>>(out, out + Bn * 40, Bn, 40);
}